// Round 8
// baseline (3401.825 us; speedup 1.0000x reference)
//
#include <hip/hip_runtime.h>
#include <stdint.h>

// ====== variant switches for XLA:CPU transcendental reconstruction ======
// (verified bit-exact in round 1 — DO NOT change the math)
#define XLA_LOG_TAIL_A 1
#define XLA_USE_FMA    0

#if XLA_USE_FMA
#define MADD(a,b,c) __builtin_fmaf((a),(b),(c))
#else
#define MADD(a,b,c) ((a)*(b)+(c))
#endif

#define N_NEUR 2048
#define HALF_N 1024
#define CKPT   125      // checkpoint/segment length for the replay pass

// ---------------- threefry2x32 (exact JAX primitive) ----------------
__device__ __forceinline__ uint32_t rotl32(uint32_t x, int r) {
  return (x << r) | (x >> (32 - r));
}

__device__ __forceinline__ void tf2x32(uint32_t k0, uint32_t k1,
                                       uint32_t& x0, uint32_t& x1) {
  const uint32_t k2 = k0 ^ k1 ^ 0x1BD11BDAu;
  x0 += k0; x1 += k1;
#define TF_R(r) { x0 += x1; x1 = rotl32(x1, r); x1 ^= x0; }
  TF_R(13) TF_R(15) TF_R(26) TF_R(6)
  x0 += k1; x1 += k2 + 1u;
  TF_R(17) TF_R(29) TF_R(16) TF_R(24)
  x0 += k2; x1 += k0 + 2u;
  TF_R(13) TF_R(15) TF_R(26) TF_R(6)
  x0 += k0; x1 += k1 + 3u;
  TF_R(17) TF_R(29) TF_R(16) TF_R(24)
  x0 += k1; x1 += k2 + 4u;
  TF_R(13) TF_R(15) TF_R(26) TF_R(6)
  x0 += k2; x1 += k0 + 5u;
#undef TF_R
}

__device__ __forceinline__ float u01_from_bits(uint32_t bits) {
#pragma clang fp contract(off)
  float f = __uint_as_float((bits >> 9) | 0x3f800000u);
  return f - 1.0f;
}

// ---------------- XLA:CPU GenerateVF32Log (Cephes, Estrin poly) ----------------
__device__ __forceinline__ float xla_log(float xin) {
#pragma clang fp contract(off)
  float t0 = fmaxf(xin, __uint_as_float(0x00800000u));
  uint32_t bits = __float_as_uint(t0);
  int em = (int)(bits >> 23) - 127;
  t0 = __uint_as_float((bits & 0x807fffffu) | 0x3f000000u);
  float e = 1.0f + (float)em;
  const bool mlt = t0 < (float)0.707106781186547524;
  float tmp1 = mlt ? t0 : 0.0f;
  t0 = t0 - 1.0f;
  e = e - (mlt ? 1.0f : 0.0f);
  t0 = t0 + tmp1;
  float x2 = t0 * t0;
  float x3 = x2 * t0;
  float y  = MADD(t0, (float)7.0376836292E-2, (float)-1.1514610310E-1);
  float ya = MADD(t0, (float)-1.2420140846E-1, (float)1.4249322787E-1);
  float yb = MADD(t0, (float)2.0000714765E-1, (float)-2.4999993993E-1);
  y  = MADD(y,  t0, (float)1.1676998740E-1);
  ya = MADD(ya, t0, (float)-1.6668057665E-1);
  yb = MADD(yb, t0, (float)3.3333331174E-1);
  y  = MADD(y, x3, ya);
  y  = MADD(y, x3, yb);
  y  = y * x3;
  float ey1 = e * (float)-2.12194440e-4;
  float hx2 = x2 * 0.5f;
  y = y + ey1;
  t0 = t0 - hx2;
  float ey2 = e * (float)0.693359375;
#if XLA_LOG_TAIL_A
  t0 = t0 + y;
  t0 = t0 + ey2;
#else
  t0 = t0 + ey2;
  t0 = t0 + y;
#endif
  if (xin == 0.0f) return -__builtin_inff();
  return t0;
}

// ---------------- XLA:CPU GenerateVF32Exp (old Cephes structure) ----------------
__device__ __forceinline__ float xla_exp(float xin) {
#pragma clang fp contract(off)
  float x = fmaxf(xin, (float)-88.3762626647949);
  x = fminf(x, (float)88.3762626647950);
  float fx = floorf(MADD(x, (float)1.44269504088896341, 0.5f));
  float tmp = (float)0.693359375 * fx;
  float z = (float)-2.12194440e-4 * fx;
  x = x - tmp;
  x = x - z;
  z = x * x;
  float y = MADD(x, (float)1.9875691500E-4, (float)1.3981999507E-3);
  y = MADD(y, x, (float)8.3334519073E-3);
  y = MADD(y, x, (float)4.1665795894E-2);
  y = MADD(y, x, (float)1.6666665459E-1);
  y = MADD(y, x, (float)5.0000001201E-1);
  y = MADD(y, z, x);
  y = 1.0f + y;
  int n = (int)fx;
  float p2n = __uint_as_float((uint32_t)(n + 127) << 23);
  return fmaxf(y * p2n, xin);
}

__device__ __forceinline__ float xla_log1p(float x) {
#pragma clang fp contract(off)
  float fl = xla_log(x + 1.0f);
  float fs = ((-0.5f * x) + 1.0f) * x;
  return (fabsf(x) < (float)1e-4) ? fs : fl;
}

// jax.nn.softplus(v) = max(v,0) + log1p(exp(-|v|))
__device__ __forceinline__ float softplus_xla(float v) {
#pragma clang fp contract(off)
  // exact shortcut: for v>=16, exp(-v)<=1.13e-7 < ulp(v)/2 -> sum rounds to v
  if (v >= 16.0f) return v;
  float a = fabsf(v);
  float ex = xla_exp(-a);
  float lp = xla_log1p(ex);
  return fmaxf(v, 0.0f) + lp;
}

// ---------------- init: tevents/yevents = +inf, event_types = 0 ----------------
__global__ void snn_init(float* __restrict__ out, size_t inf_base,
                         size_t inf_cnt, size_t zero_cnt) {
  size_t i = (size_t)blockIdx.x * blockDim.x + threadIdx.x;
  size_t stride = (size_t)gridDim.x * blockDim.x;
  size_t total = inf_cnt + zero_cnt;
  for (size_t k = i; k < total; k += stride) {
    out[inf_base + k] = (k < inf_cnt) ? __builtin_inff() : 0.0f;
  }
}

// ---------------- precompute s_reset[step][j] = log(u)-alpha into sres ---------
__global__ __launch_bounds__(1024)
void snn_pre(const int* __restrict__ seedp, float* __restrict__ sres) {
#pragma clang fp contract(off)
  const int step = blockIdx.x;       // 0..T-2
  const int t = threadIdx.x;
  uint32_t seed = (uint32_t)seedp[0];
  uint32_t a0 = 0u, a1 = 2u; tf2x32(0u, seed, a0, a1);
  uint32_t b0 = 1u, b1 = 3u; tf2x32(0u, seed, b0, b1);
  uint32_t f0 = 0u, f1 = (uint32_t)step; tf2x32(a1, b1, f0, f1);
  uint32_t d0 = (uint32_t)t, d1 = (uint32_t)(t + HALF_N);
  tf2x32(f0, f1, d0, d1);
  float srA = xla_log(u01_from_bits(d0)) - 0.01f;
  float srB = xla_log(u01_from_bits(d1)) - 0.01f;
  sres[(size_t)step * N_NEUR + t] = srA;
  sres[(size_t)step * N_NEUR + HALF_N + t] = srB;
}

// ============ PHASE A: decision chain only (1 block, 512 thr, 4 n/t) ==========
// 8 waves. Atomic-free reduce: lane0 of each wave ds_writes its candidate to
// slot[k&1][wave] (written EVERY step -> no reset); one barrier; everyone reads
// 8 slots via 2x b128 + 7 v_min. Pending-i (w row consumed next step).
__global__ __launch_bounds__(512, 1)
void snn_evt(const float* __restrict__ ts, const float* __restrict__ v0,
             const float* __restrict__ i0, const float* __restrict__ ic,
             const float* __restrict__ w, const float* __restrict__ mu,
             const int* __restrict__ seedp, const float* __restrict__ sres,
             uint32_t* __restrict__ spk, float* __restrict__ out, int T, int MS) {
#pragma clang fp contract(off)
  const int tid = threadIdx.x;
  const int nb = tid * 4;               // neurons nb..nb+3
  const int wave = tid >> 6;            // 0..7
  const int lane = tid & 63;

  float* ys   = out;                                     // [T][N][3]
  float* tev  = out + (size_t)T * N_NEUR * 3;            // [MS]
  float* etv  = tev + (size_t)MS + (size_t)MS * N_NEUR * 3;
  float* nspp = etv + (size_t)MS * N_NEUR;               // [1]

  // keys
  uint32_t seed = (uint32_t)seedp[0];
  uint32_t a0 = 0u, a1 = 2u; tf2x32(0u, seed, a0, a1);
  uint32_t b0 = 1u, b1 = 3u; tf2x32(0u, seed, b0, b1);
  const uint32_t ki0 = a0, ki1 = b0;

  float vv[4], ipd[4], ss[4], icv[4], wvp[4];
  {
    float4 x = *(const float4*)&v0[nb];
    vv[0]=x.x; vv[1]=x.y; vv[2]=x.z; vv[3]=x.w;
  }
  {
    float4 x = *(const float4*)&i0[nb];
    ipd[0]=x.x; ipd[1]=x.y; ipd[2]=x.z; ipd[3]=x.w;
  }
  {
    float4 x = *(const float4*)&ic[nb];
    icv[0]=x.x; icv[1]=x.y; icv[2]=x.z; icv[3]=x.w;
  }
#pragma unroll
  for (int q = 0; q < 4; ++q) {
    int j = nb + q;
    uint32_t c0 = (uint32_t)(j < HALF_N ? j : j - HALF_N);
    uint32_t c1 = c0 + HALF_N;
    tf2x32(ki0, ki1, c0, c1);
    ss[q] = xla_log(u01_from_bits(j < HALF_N ? c0 : c1)) - 0.01f;
    wvp[q] = 0.0f;
  }
  const float m0 = mu[0], m1 = mu[1];

  __shared__ alignas(16) uint32_t slot[2][8];
  if (tid < 16) ((uint32_t*)slot)[tid] = 0xFFFFFFFFu;
  __syncthreads();

  int nsp = 0;
  bool hasPrev = false;
  float tp = ts[0];
  float tn = ts[1];
  int next_ck = 0;

  for (int k = 0; k < T - 1; ++k) {
    const float dt = tn - tp;

    // next-ts prefetch (uniform, cheap)
    float tn_nx = ts[(k + 2 < T) ? (k + 2) : (T - 1)];
    // reset-value row for this step (consumed post-barrier -> natural slack)
    float4 srv = *(const float4*)(sres + (size_t)k * N_NEUR + nb);
    float sr[4] = {srv.x, srv.y, srv.z, srv.w};

    // resolve committed i_k (consumes w row issued at step k-1)
    float ii[4];
#pragma unroll
    for (int q = 0; q < 4; ++q) ii[q] = hasPrev ? (ipd[q] + wvp[q]) : ipd[q];

    // checkpoint row (rare, uniform branch)
    if (k == next_ck) {
      float* yr = ys + ((size_t)k * N_NEUR + nb) * 3;
      ((float4*)yr)[0] = make_float4(vv[0], ii[0], ss[0], vv[1]);
      ((float4*)yr)[1] = make_float4(ii[1], ss[1], vv[2], ii[2]);
      ((float4*)yr)[2] = make_float4(ss[2], vv[3], ii[3], ss[3]);
      next_ck += CKPT;
    }

    // event chain (expressions verbatim from verified kernel)
    float y1s[4];
    bool ev[4];
#pragma unroll
    for (int q = 0; q < 4; ++q) {
      float sp = softplus_xla(vv[q]);
      y1s[q] = ss[q] + dt * sp;
      ev[q] = (y1s[q] >= 0.0f);
    }

    // per-thread min event index (0..3, 4=none) -> wave candidate -> slot write
    int lidx = 4;
    if (ev[3]) lidx = 3;
    if (ev[2]) lidx = 2;
    if (ev[1]) lidx = 1;
    if (ev[0]) lidx = 0;
    unsigned long long bm = __ballot(lidx < 4);
    if (lane == 0) {
      uint32_t cand = 0xFFFFFFFFu;
      if (bm) {
        int fl = __builtin_ctzll(bm);
        cand = (uint32_t)__builtin_amdgcn_readlane(nb + lidx, fl);
      }
      slot[k & 1][wave] = cand;
    }

    // Euler v,i updates (independent of reduce; overlaps barrier)
    float y1v[4], y1i[4];
#pragma unroll
    for (int q = 0; q < 4; ++q) {
      float dv = m0 * ((ii[q] + icv[q]) - vv[q]);
      y1v[q] = vv[q] + dt * dv;
      y1i[q] = ii[q] + dt * ((-m1) * ii[q]);
    }

    __syncthreads();

    // read 8 slots, min-reduce in-register
    uint32_t gmin;
    {
      const uint4* rp = (const uint4*)&slot[k & 1][0];
      uint4 r0 = rp[0], r1 = rp[1];
      uint32_t a = r0.x < r0.y ? r0.x : r0.y;
      uint32_t b = r0.z < r0.w ? r0.z : r0.w;
      uint32_t c = r1.x < r1.y ? r1.x : r1.y;
      uint32_t d = r1.z < r1.w ? r1.z : r1.w;
      a = a < b ? a : b;
      c = c < d ? c : d;
      gmin = a < c ? a : c;
    }
    gmin = (uint32_t)__builtin_amdgcn_readfirstlane((int)gmin);
    const bool has = (gmin != 0xFFFFFFFFu);

    // issue w row load for THIS step (consumed next iteration)
    float wn[4] = {0.0f, 0.0f, 0.0f, 0.0f};
    if (has) {
      float4 x = *(const float4*)&w[((size_t)gmin << 11) + nb];
      wn[0]=x.x; wn[1]=x.y; wn[2]=x.z; wn[3]=x.w;
    }

    // bookkeeping (tid0)
    if (tid == 0) {
      spk[k] = ((uint32_t)nsp << 16) | (has ? (gmin & 0xFFFFu) : 0xFFFFu);
      if (has && nsp < MS) tev[nsp] = tn;
    }
    nsp += has ? 1 : 0;

    // commit (ev ⊆ has)
#pragma unroll
    for (int q = 0; q < 4; ++q) {
      vv[q] = y1v[q] - (ev[q] ? 1.0f : 0.0f);
      ss[q] = ev[q] ? sr[q] : y1s[q];
      ipd[q] = y1i[q];
      wvp[q] = wn[q];
    }
    hasPrev = has;
    tp = tn; tn = tn_nx;
  }

  if (tid == 0) nspp[0] = (float)nsp;
}

// ============ PHASE B: parallel replay (32 segs x 2 halves, 1 n/t) ============
__global__ __launch_bounds__(1024, 1)
void snn_rep(const float* __restrict__ ts, const float* __restrict__ ic,
             const float* __restrict__ w, const float* __restrict__ mu,
             const float* __restrict__ sres, const uint32_t* __restrict__ spk,
             float* __restrict__ out, int T, int MS) {
#pragma clang fp contract(off)
  const int seg = blockIdx.x >> 1;
  const int gn = (blockIdx.x & 1) * 1024 + threadIdx.x;
  const int lo = seg * CKPT;
  const int end = min(lo + CKPT, T - 1);

  float* ys  = out;                                      // [T][N][3]
  float* tev = out + (size_t)T * N_NEUR * 3;
  float* yev = tev + (size_t)MS;                         // [MS][N][3]
  float* etv = yev + (size_t)MS * N_NEUR * 3;            // [MS][N]

  // start from phase-A checkpoint = committed y at step lo
  const float* y0r = ys + ((size_t)lo * N_NEUR + gn) * 3;
  float vv = y0r[0];
  float ii = y0r[1];
  float ss = y0r[2];
  const float icv = ic[gn];
  const float m0 = mu[0], m1 = mu[1];
  float tp = ts[lo];

  for (int k = lo; k < end; ++k) {
    const float tn = ts[k + 1];
    const float dt = tn - tp;
    tp = tn;
    const uint32_t pk = spk[k];

    // identical expression chain -> bit-exact state replay
    float sp  = softplus_xla(vv);
    float y1s = ss + dt * sp;
    const bool ev = (y1s >= 0.0f);
    float dv  = m0 * ((ii + icv) - vv);
    float y1v = vv + dt * dv;
    float y1i = ii + dt * ((-m1) * ii);

    const uint32_t e16 = pk & 0xFFFFu;
    const bool has = (e16 != 0xFFFFu);
    const uint32_t nsp = pk >> 16;

    float wv = 0.0f;
    if (has) wv = w[((size_t)e16 << 11) + gn];

    if (has && nsp < (uint32_t)MS) {
      float* ye = yev + ((size_t)nsp * N_NEUR + gn) * 3;
      ye[0] = y1v; ye[1] = y1i; ye[2] = y1s;
      etv[(size_t)nsp * N_NEUR + gn] = ev ? 1.0f : 0.0f;
    }

    ii = has ? (y1i + wv) : y1i;
    vv = y1v - (ev ? 1.0f : 0.0f);
    if (ev) ss = sres[(size_t)k * N_NEUR + gn]; else ss = y1s;

    float* yr = ys + ((size_t)(k + 1) * N_NEUR + gn) * 3;
    yr[0] = vv; yr[1] = ii; yr[2] = ss;
  }
}

// ============ FALLBACK: R5 single-kernel scan (if workspace too small) ========
template <bool USE_SRES>
__global__ __launch_bounds__(1024, 1)
void snn_sim(const float* __restrict__ ts, const float* __restrict__ v0,
             const float* __restrict__ i0, const float* __restrict__ ic,
             const float* __restrict__ w, const float* __restrict__ mu,
             const int* __restrict__ seedp, const float* __restrict__ sres,
             float* __restrict__ out, int T, int MS) {
#pragma clang fp contract(off)
  const int tid = threadIdx.x;
  const int nb = tid * 2;
  const int lane = tid & 63;

  float* ys   = out;
  float* tev  = out + (size_t)T * N_NEUR * 3;
  float* yev  = tev + (size_t)MS;
  float* etv  = yev + (size_t)MS * N_NEUR * 3;
  float* nspp = etv + (size_t)MS * N_NEUR;

  uint32_t seed = (uint32_t)seedp[0];
  uint32_t a0 = 0u, a1 = 2u; tf2x32(0u, seed, a0, a1);
  uint32_t b0 = 1u, b1 = 3u; tf2x32(0u, seed, b0, b1);
  const uint32_t ki0 = a0, ki1 = b0;
  const uint32_t kt0 = a1, kt1 = b1;

  float vv0, vv1, ii0, ii1, ss0, ss1, icv0, icv1;
  { float2 x = *(const float2*)&v0[nb]; vv0 = x.x; vv1 = x.y; }
  { float2 x = *(const float2*)&i0[nb]; ii0 = x.x; ii1 = x.y; }
  { float2 x = *(const float2*)&ic[nb]; icv0 = x.x; icv1 = x.y; }
  {
    uint32_t c0 = (uint32_t)(nb < HALF_N ? nb : nb - HALF_N);
    uint32_t c1 = c0 + HALF_N;
    tf2x32(ki0, ki1, c0, c1);
    ss0 = xla_log(u01_from_bits(nb < HALF_N ? c0 : c1)) - 0.01f;
  }
  {
    int j = nb + 1;
    uint32_t c0 = (uint32_t)(j < HALF_N ? j : j - HALF_N);
    uint32_t c1 = c0 + HALF_N;
    tf2x32(ki0, ki1, c0, c1);
    ss1 = xla_log(u01_from_bits(j < HALF_N ? c0 : c1)) - 0.01f;
  }
  const float m0 = mu[0], m1 = mu[1];

  {
    float* yr = ys + (size_t)nb * 3;
    ((float2*)yr)[0] = make_float2(vv0, ii0);
    ((float2*)yr)[1] = make_float2(ss0, vv1);
    ((float2*)yr)[2] = make_float2(ii1, ss1);
  }

  __shared__ uint32_t slot[4];
  if (tid < 4) slot[tid] = 0xFFFFFFFFu;
  __syncthreads();

  int nsp = 0;
  float tp = ts[0];
  const float* srp = USE_SRES ? (sres + nb) : nullptr;
  float* yrow = ys + (size_t)N_NEUR * 3 + (size_t)nb * 3;

  for (int k = 0; k < T - 1; ++k) {
    const float tn = ts[k + 1];
    const float dt = tn - tp;
    tp = tn;

    float sr0 = 0.0f, sr1 = 0.0f;
    if (USE_SRES) {
      float2 x = *(const float2*)srp;
      sr0 = x.x; sr1 = x.y;
      srp += N_NEUR;
    }

    float sp0 = softplus_xla(vv0);
    float sp1 = softplus_xla(vv1);
    float y1s0 = ss0 + dt * sp0;
    float y1s1 = ss1 + dt * sp1;
    const bool ev0 = (y1s0 >= 0.0f);
    const bool ev1 = (y1s1 >= 0.0f);

    int lidx = ev0 ? 0 : (ev1 ? 1 : 2);
    unsigned long long bm = __ballot(lidx < 2);
    if (lane == 0 && bm) {
      int fl = __builtin_ctzll(bm);
      uint32_t cand = (uint32_t)__builtin_amdgcn_readlane(nb + lidx, fl);
      atomicMin(&slot[k & 3], cand);
    }
    if (tid == 0) slot[(k + 1) & 3] = 0xFFFFFFFFu;

    float dv0 = m0 * ((ii0 + icv0) - vv0);
    float dv1 = m0 * ((ii1 + icv1) - vv1);
    float y1v0 = vv0 + dt * dv0;
    float y1v1 = vv1 + dt * dv1;
    float y1i0 = ii0 + dt * ((-m1) * ii0);
    float y1i1 = ii1 + dt * ((-m1) * ii1);

    __syncthreads();

    uint32_t gmin = (uint32_t)__builtin_amdgcn_readfirstlane((int)slot[k & 3]);
    const bool has = (gmin != 0xFFFFFFFFu);

    float wv0 = 0.0f, wv1 = 0.0f;
    if (has) {
      float2 x = *(const float2*)&w[((size_t)gmin << 11) + nb];
      wv0 = x.x; wv1 = x.y;
    }

    if (has && nsp < MS) {
      if (tid == 0) tev[nsp] = tn;
      float* ye = yev + ((size_t)nsp * N_NEUR + nb) * 3;
      ((float2*)ye)[0] = make_float2(y1v0, y1i0);
      ((float2*)ye)[1] = make_float2(y1s0, y1v1);
      ((float2*)ye)[2] = make_float2(y1i1, y1s1);
      *(float2*)(etv + (size_t)nsp * N_NEUR + nb) =
          make_float2(ev0 ? 1.0f : 0.0f, ev1 ? 1.0f : 0.0f);
    }
    nsp += has ? 1 : 0;

    ii0 = has ? (y1i0 + wv0) : y1i0;
    ii1 = has ? (y1i1 + wv1) : y1i1;
    vv0 = y1v0 - (ev0 ? 1.0f : 0.0f);
    vv1 = y1v1 - (ev1 ? 1.0f : 0.0f);
    if (USE_SRES) {
      ss0 = ev0 ? sr0 : y1s0;
      ss1 = ev1 ? sr1 : y1s1;
    } else {
      ss0 = y1s0; ss1 = y1s1;
      if (ev0 | ev1) {
        uint32_t f0 = 0u, f1 = (uint32_t)k;
        tf2x32(kt0, kt1, f0, f1);
        if (ev0) {
          uint32_t c0 = (uint32_t)(nb < HALF_N ? nb : nb - HALF_N);
          uint32_t c1 = c0 + HALF_N;
          tf2x32(f0, f1, c0, c1);
          ss0 = xla_log(u01_from_bits(nb < HALF_N ? c0 : c1)) - 0.01f;
        }
        if (ev1) {
          int j = nb + 1;
          uint32_t c0 = (uint32_t)(j < HALF_N ? j : j - HALF_N);
          uint32_t c1 = c0 + HALF_N;
          tf2x32(f0, f1, c0, c1);
          ss1 = xla_log(u01_from_bits(j < HALF_N ? c0 : c1)) - 0.01f;
        }
      }
    }

    ((float2*)yrow)[0] = make_float2(vv0, ii0);
    ((float2*)yrow)[1] = make_float2(ss0, vv1);
    ((float2*)yrow)[2] = make_float2(ii1, ss1);
    yrow += (size_t)N_NEUR * 3;
  }

  if (tid == 0) nspp[0] = (float)nsp;
}

extern "C" void kernel_launch(void* const* d_in, const int* in_sizes, int n_in,
                              void* d_out, int out_size, void* d_ws, size_t ws_size,
                              hipStream_t stream) {
  const float* ts = (const float*)d_in[0];
  const float* v0 = (const float*)d_in[1];
  const float* i0 = (const float*)d_in[2];
  const float* ic = (const float*)d_in[3];
  const float* w  = (const float*)d_in[4];
  const float* mu = (const float*)d_in[5];
  const int* seed = (const int*)d_in[6];

  const int T = in_sizes[0];      // 4000
  const int N = in_sizes[1];      // 2048
  long long rem = (long long)out_size - (long long)T * N * 3 - 1;
  int MS = (int)(rem / (1 + 4 * (long long)N));
  if (MS <= 0) MS = 512;

  size_t inf_base = (size_t)T * N * 3;
  size_t inf_cnt  = (size_t)MS + (size_t)MS * N * 3;
  size_t zero_cnt = (size_t)MS * N;
  snn_init<<<dim3(512), dim3(256), 0, stream>>>((float*)d_out, inf_base, inf_cnt, zero_cnt);

  // ws layout: [0, sres_bytes) = sres; [sres_bytes, +4*(T-1)) = spk
  size_t sres_bytes = (size_t)(T - 1) * (size_t)N * sizeof(float);
  size_t full_bytes = sres_bytes + (size_t)(T - 1) * sizeof(uint32_t);

  if (ws_size >= full_bytes) {
    float* sres = (float*)d_ws;
    uint32_t* spk = (uint32_t*)((char*)d_ws + sres_bytes);
    snn_pre<<<dim3(T - 1), dim3(1024), 0, stream>>>(seed, sres);
    snn_evt<<<dim3(1), dim3(512), 0, stream>>>(ts, v0, i0, ic, w, mu, seed,
                                               sres, spk, (float*)d_out, T, MS);
    int nseg = (T - 1 + CKPT - 1) / CKPT;
    snn_rep<<<dim3(nseg * 2), dim3(1024), 0, stream>>>(ts, ic, w, mu, sres, spk,
                                                       (float*)d_out, T, MS);
  } else if (ws_size >= sres_bytes) {
    snn_pre<<<dim3(T - 1), dim3(1024), 0, stream>>>(seed, (float*)d_ws);
    snn_sim<true><<<dim3(1), dim3(1024), 0, stream>>>(ts, v0, i0, ic, w, mu, seed,
                                                      (const float*)d_ws,
                                                      (float*)d_out, T, MS);
  } else {
    snn_sim<false><<<dim3(1), dim3(1024), 0, stream>>>(ts, v0, i0, ic, w, mu, seed,
                                                       nullptr, (float*)d_out, T, MS);
  }
}

// Round 9
// 3097.192 us; speedup vs baseline: 1.0984x; 1.0984x over previous
//
#include <hip/hip_runtime.h>
#include <stdint.h>

// ====== variant switches for XLA:CPU transcendental reconstruction ======
// (verified bit-exact in round 1 — DO NOT change the math)
#define XLA_LOG_TAIL_A 1
#define XLA_USE_FMA    0

#if XLA_USE_FMA
#define MADD(a,b,c) __builtin_fmaf((a),(b),(c))
#else
#define MADD(a,b,c) ((a)*(b)+(c))
#endif

#define N_NEUR 2048
#define HALF_N 1024
#define CKPT   124      // even: checkpoints land on even (pair-start) steps

// ---------------- threefry2x32 (exact JAX primitive) ----------------
__device__ __forceinline__ uint32_t rotl32(uint32_t x, int r) {
  return (x << r) | (x >> (32 - r));
}

__device__ __forceinline__ void tf2x32(uint32_t k0, uint32_t k1,
                                       uint32_t& x0, uint32_t& x1) {
  const uint32_t k2 = k0 ^ k1 ^ 0x1BD11BDAu;
  x0 += k0; x1 += k1;
#define TF_R(r) { x0 += x1; x1 = rotl32(x1, r); x1 ^= x0; }
  TF_R(13) TF_R(15) TF_R(26) TF_R(6)
  x0 += k1; x1 += k2 + 1u;
  TF_R(17) TF_R(29) TF_R(16) TF_R(24)
  x0 += k2; x1 += k0 + 2u;
  TF_R(13) TF_R(15) TF_R(26) TF_R(6)
  x0 += k0; x1 += k1 + 3u;
  TF_R(17) TF_R(29) TF_R(16) TF_R(24)
  x0 += k1; x1 += k2 + 4u;
  TF_R(13) TF_R(15) TF_R(26) TF_R(6)
  x0 += k2; x1 += k0 + 5u;
#undef TF_R
}

__device__ __forceinline__ float u01_from_bits(uint32_t bits) {
#pragma clang fp contract(off)
  float f = __uint_as_float((bits >> 9) | 0x3f800000u);
  return f - 1.0f;
}

// ---------------- XLA:CPU GenerateVF32Log (Cephes, Estrin poly) ----------------
__device__ __forceinline__ float xla_log(float xin) {
#pragma clang fp contract(off)
  float t0 = fmaxf(xin, __uint_as_float(0x00800000u));
  uint32_t bits = __float_as_uint(t0);
  int em = (int)(bits >> 23) - 127;
  t0 = __uint_as_float((bits & 0x807fffffu) | 0x3f000000u);
  float e = 1.0f + (float)em;
  const bool mlt = t0 < (float)0.707106781186547524;
  float tmp1 = mlt ? t0 : 0.0f;
  t0 = t0 - 1.0f;
  e = e - (mlt ? 1.0f : 0.0f);
  t0 = t0 + tmp1;
  float x2 = t0 * t0;
  float x3 = x2 * t0;
  float y  = MADD(t0, (float)7.0376836292E-2, (float)-1.1514610310E-1);
  float ya = MADD(t0, (float)-1.2420140846E-1, (float)1.4249322787E-1);
  float yb = MADD(t0, (float)2.0000714765E-1, (float)-2.4999993993E-1);
  y  = MADD(y,  t0, (float)1.1676998740E-1);
  ya = MADD(ya, t0, (float)-1.6668057665E-1);
  yb = MADD(yb, t0, (float)3.3333331174E-1);
  y  = MADD(y, x3, ya);
  y  = MADD(y, x3, yb);
  y  = y * x3;
  float ey1 = e * (float)-2.12194440e-4;
  float hx2 = x2 * 0.5f;
  y = y + ey1;
  t0 = t0 - hx2;
  float ey2 = e * (float)0.693359375;
#if XLA_LOG_TAIL_A
  t0 = t0 + y;
  t0 = t0 + ey2;
#else
  t0 = t0 + ey2;
  t0 = t0 + y;
#endif
  if (xin == 0.0f) return -__builtin_inff();
  return t0;
}

// ---------------- XLA:CPU GenerateVF32Exp (old Cephes structure) ----------------
__device__ __forceinline__ float xla_exp(float xin) {
#pragma clang fp contract(off)
  float x = fmaxf(xin, (float)-88.3762626647949);
  x = fminf(x, (float)88.3762626647950);
  float fx = floorf(MADD(x, (float)1.44269504088896341, 0.5f));
  float tmp = (float)0.693359375 * fx;
  float z = (float)-2.12194440e-4 * fx;
  x = x - tmp;
  x = x - z;
  z = x * x;
  float y = MADD(x, (float)1.9875691500E-4, (float)1.3981999507E-3);
  y = MADD(y, x, (float)8.3334519073E-3);
  y = MADD(y, x, (float)4.1665795894E-2);
  y = MADD(y, x, (float)1.6666665459E-1);
  y = MADD(y, x, (float)5.0000001201E-1);
  y = MADD(y, z, x);
  y = 1.0f + y;
  int n = (int)fx;
  float p2n = __uint_as_float((uint32_t)(n + 127) << 23);
  return fmaxf(y * p2n, xin);
}

__device__ __forceinline__ float xla_log1p(float x) {
#pragma clang fp contract(off)
  float fl = xla_log(x + 1.0f);
  float fs = ((-0.5f * x) + 1.0f) * x;
  return (fabsf(x) < (float)1e-4) ? fs : fl;
}

// jax.nn.softplus(v) = max(v,0) + log1p(exp(-|v|))
__device__ __forceinline__ float softplus_xla(float v) {
#pragma clang fp contract(off)
  // exact shortcut: for v>=16, exp(-v)<=1.13e-7 < ulp(v)/2 -> sum rounds to v
  if (v >= 16.0f) return v;
  float a = fabsf(v);
  float ex = xla_exp(-a);
  float lp = xla_log1p(ex);
  return fmaxf(v, 0.0f) + lp;
}

// ---------------- init: tevents/yevents = +inf, event_types = 0 ----------------
__global__ void snn_init(float* __restrict__ out, size_t inf_base,
                         size_t inf_cnt, size_t zero_cnt) {
  size_t i = (size_t)blockIdx.x * blockDim.x + threadIdx.x;
  size_t stride = (size_t)gridDim.x * blockDim.x;
  size_t total = inf_cnt + zero_cnt;
  for (size_t k = i; k < total; k += stride) {
    out[inf_base + k] = (k < inf_cnt) ? __builtin_inff() : 0.0f;
  }
}

// ---------------- precompute s_reset[step][j] = log(u)-alpha into sres ---------
__global__ __launch_bounds__(1024)
void snn_pre(const int* __restrict__ seedp, float* __restrict__ sres) {
#pragma clang fp contract(off)
  const int step = blockIdx.x;       // 0..T-2
  const int t = threadIdx.x;
  uint32_t seed = (uint32_t)seedp[0];
  uint32_t a0 = 0u, a1 = 2u; tf2x32(0u, seed, a0, a1);
  uint32_t b0 = 1u, b1 = 3u; tf2x32(0u, seed, b0, b1);
  uint32_t f0 = 0u, f1 = (uint32_t)step; tf2x32(a1, b1, f0, f1);
  uint32_t d0 = (uint32_t)t, d1 = (uint32_t)(t + HALF_N);
  tf2x32(f0, f1, d0, d1);
  float srA = xla_log(u01_from_bits(d0)) - 0.01f;
  float srB = xla_log(u01_from_bits(d1)) - 0.01f;
  sres[(size_t)step * N_NEUR + t] = srA;
  sres[(size_t)step * N_NEUR + HALF_N + t] = srB;
}

// ============ PHASE A: decision chain, 2 steps per barrier =====================
// 512 thr x 4 contiguous neurons. Per pair (steps e=2P, o=2P+1):
//  pre-barrier: finish deferred Euler of step o_prev (w arrived last pair),
//  commit v/s at e, compute ev_e AND ev_o (lane-local), post both candidates.
//  post-barrier: combined minima for e,o; issue w loads (consumed next pair).
__global__ __launch_bounds__(512, 1)
void snn_evt(const float* __restrict__ ts, const float* __restrict__ v0,
             const float* __restrict__ i0, const float* __restrict__ ic,
             const float* __restrict__ w, const float* __restrict__ mu,
             const int* __restrict__ seedp, const float* __restrict__ sres,
             uint32_t* __restrict__ spk, float* __restrict__ out, int T, int MS) {
#pragma clang fp contract(off)
  const int tid = threadIdx.x;
  const int nb = tid * 4;               // neurons nb..nb+3
  const int wave = tid >> 6;            // 0..7
  const int lane = tid & 63;

  float* ys   = out;                                     // [T][N][3]
  float* tev  = out + (size_t)T * N_NEUR * 3;            // [MS]
  float* etv  = tev + (size_t)MS + (size_t)MS * N_NEUR * 3;
  float* nspp = etv + (size_t)MS * N_NEUR;               // [1]

  // keys
  uint32_t seed = (uint32_t)seedp[0];
  uint32_t a0 = 0u, a1 = 2u; tf2x32(0u, seed, a0, a1);
  uint32_t b0 = 1u, b1 = 3u; tf2x32(0u, seed, b0, b1);
  const uint32_t ki0 = a0, ki1 = b0;

  const float m0 = mu[0], m1 = mu[1];

  // ---- carried state (suffix: E = even step committed, O = odd step) ----
  float vvO[4];        // v at step o_prev (committed)
  float ssE[4];        // s at step e (committed)
  bool  evO[4];        // ev at step o_prev
  float y1iP[4];       // y1i of step e_prev (pending i)
  float wEp[4], wOp[4];  // w rows for eidx at e_prev / o_prev
  bool  hasEp = false, hasOp = false;
  float dtOp = 0.0f;   // dt of step o_prev (0 => prologue zero-dt trick)
  float icv[4];
  float srE[4], srO[4];  // sres rows for steps e, o

  {
    float4 x = *(const float4*)&v0[nb];
    vvO[0]=x.x; vvO[1]=x.y; vvO[2]=x.z; vvO[3]=x.w;
  }
  {
    float4 x = *(const float4*)&i0[nb];
    y1iP[0]=x.x; y1iP[1]=x.y; y1iP[2]=x.z; y1iP[3]=x.w;
  }
  {
    float4 x = *(const float4*)&ic[nb];
    icv[0]=x.x; icv[1]=x.y; icv[2]=x.z; icv[3]=x.w;
  }
#pragma unroll
  for (int q = 0; q < 4; ++q) {
    int j = nb + q;
    uint32_t c0 = (uint32_t)(j < HALF_N ? j : j - HALF_N);
    uint32_t c1 = c0 + HALF_N;
    tf2x32(ki0, ki1, c0, c1);
    ssE[q] = xla_log(u01_from_bits(j < HALF_N ? c0 : c1)) - 0.01f;
    evO[q] = false;
    wEp[q] = 0.0f; wOp[q] = 0.0f;
  }
  {
    float4 x = *(const float4*)(sres + nb);
    srE[0]=x.x; srE[1]=x.y; srE[2]=x.z; srE[3]=x.w;
  }
  {
    float4 x = *(const float4*)(sres + N_NEUR + nb);
    srO[0]=x.x; srO[1]=x.y; srO[2]=x.z; srO[3]=x.w;
  }

  __shared__ alignas(16) uint32_t slot[2][16];   // [pair&1][wave*2 + {E,O}]
  __syncthreads();

  int nsp = 0;
  int next_ck = 0;
  float tsE = ts[0];
  const int pairs = (T - 1) >> 1;       // full pairs
  const int last_row = T - 2;           // max valid sres row

  for (int P = 0; P < pairs; ++P) {
    const int e = 2 * P;

    // ---- A: finish deferred step o_prev ----
    float vvE[4], iiE[4], y1iO_[4];
#pragma unroll
    for (int q = 0; q < 4; ++q) {
      float iiO = hasEp ? (y1iP[q] + wEp[q]) : y1iP[q];
      float dv  = m0 * ((iiO + icv[q]) - vvO[q]);
      float y1v = vvO[q] + dtOp * dv;
      float y1i = iiO + dtOp * ((-m1) * iiO);
      vvE[q] = y1v - (evO[q] ? 1.0f : 0.0f);     // B: commit v at e
      y1iO_[q] = y1i;
    }
#pragma unroll
    for (int q = 0; q < 4; ++q)                   // C: i at e
      iiE[q] = hasOp ? (y1iO_[q] + wOp[q]) : y1iO_[q];

    // ---- D: checkpoint (rare, uniform) ----
    if (e == next_ck) {
      float* yr = ys + ((size_t)e * N_NEUR + nb) * 3;
      ((float4*)yr)[0] = make_float4(vvE[0], iiE[0], ssE[0], vvE[1]);
      ((float4*)yr)[1] = make_float4(iiE[1], ssE[1], vvE[2], iiE[2]);
      ((float4*)yr)[2] = make_float4(ssE[2], vvE[3], iiE[3], ssE[3]);
      next_ck += CKPT;
    }

    const float tsE1 = ts[e + 1];
    const float tsE2 = ts[e + 2];
    const float dtE = tsE1 - tsE;
    const float dtO = tsE2 - tsE1;

    // ---- E/F/G/H: two event steps, lane-local ----
    float y1iE[4], vvOn[4], ssEn[4];
    bool evE[4], evOn[4];
#pragma unroll
    for (int q = 0; q < 4; ++q) {
      float sp  = softplus_xla(vvE[q]);
      float y1s = ssE[q] + dtE * sp;
      evE[q] = (y1s >= 0.0f);
      float dv  = m0 * ((iiE[q] + icv[q]) - vvE[q]);
      float y1v = vvE[q] + dtE * dv;
      y1iE[q] = iiE[q] + dtE * ((-m1) * iiE[q]);
      vvOn[q] = y1v - (evE[q] ? 1.0f : 0.0f);
      float ssO_ = evE[q] ? srE[q] : y1s;
      float spO = softplus_xla(vvOn[q]);
      float y1sO = ssO_ + dtO * spO;
      evOn[q] = (y1sO >= 0.0f);
      ssEn[q] = evOn[q] ? srO[q] : y1sO;          // early s commit for e+2
    }

    // ---- I: candidates + next-pair sres prefetch ----
    {
      int lE = 4;
      if (evE[3]) lE = 3;
      if (evE[2]) lE = 2;
      if (evE[1]) lE = 1;
      if (evE[0]) lE = 0;
      int lO = 4;
      if (evOn[3]) lO = 3;
      if (evOn[2]) lO = 2;
      if (evOn[1]) lO = 1;
      if (evOn[0]) lO = 0;
      unsigned long long bE = __ballot(lE < 4);
      unsigned long long bO = __ballot(lO < 4);
      if (lane == 0) {
        uint32_t cE = 0xFFFFFFFFu, cO = 0xFFFFFFFFu;
        if (bE) cE = (uint32_t)__builtin_amdgcn_readlane(nb + lE, __builtin_ctzll(bE));
        if (bO) cO = (uint32_t)__builtin_amdgcn_readlane(nb + lO, __builtin_ctzll(bO));
        *(uint64_t*)&slot[P & 1][wave * 2] = ((uint64_t)cO << 32) | (uint64_t)cE;
      }
    }
    float srEn[4], srOn[4];
    {
      int re = e + 2;  if (re > last_row) re = last_row;
      int ro = e + 3;  if (ro > last_row) ro = last_row;
      float4 x = *(const float4*)(sres + (size_t)re * N_NEUR + nb);
      srEn[0]=x.x; srEn[1]=x.y; srEn[2]=x.z; srEn[3]=x.w;
      float4 y = *(const float4*)(sres + (size_t)ro * N_NEUR + nb);
      srOn[0]=y.x; srOn[1]=y.y; srOn[2]=y.z; srOn[3]=y.w;
    }

    __syncthreads();

    // ---- K: combined minima for e and o ----
    uint32_t gE, gO;
    {
      const uint4* rp = (const uint4*)&slot[P & 1][0];
      uint4 r0 = rp[0], r1 = rp[1], r2 = rp[2], r3 = rp[3];
      uint32_t a = r0.x < r1.x ? r0.x : r1.x;
      uint32_t b = r2.x < r3.x ? r2.x : r3.x;
      uint32_t c = r0.z < r1.z ? r0.z : r1.z;
      uint32_t d = r2.z < r3.z ? r2.z : r3.z;
      a = a < b ? a : b;  c = c < d ? c : d;
      gE = a < c ? a : c;
      uint32_t e1 = r0.y < r1.y ? r0.y : r1.y;
      uint32_t f1 = r2.y < r3.y ? r2.y : r3.y;
      uint32_t g1 = r0.w < r1.w ? r0.w : r1.w;
      uint32_t h1 = r2.w < r3.w ? r2.w : r3.w;
      e1 = e1 < f1 ? e1 : f1;  g1 = g1 < h1 ? g1 : h1;
      gO = e1 < g1 ? e1 : g1;
    }
    gE = (uint32_t)__builtin_amdgcn_readfirstlane((int)gE);
    gO = (uint32_t)__builtin_amdgcn_readfirstlane((int)gO);
    const bool hasE = (gE != 0xFFFFFFFFu);
    const bool hasO = (gO != 0xFFFFFFFFu);

    // ---- bookkeeping (tid0) ----
    if (tid == 0) {
      spk[e] = ((uint32_t)nsp << 16) | (hasE ? (gE & 0xFFFFu) : 0xFFFFu);
      if (hasE && nsp < MS) tev[nsp] = tsE1;
    }
    int nspE = nsp + (hasE ? 1 : 0);
    if (tid == 0) {
      spk[e + 1] = ((uint32_t)nspE << 16) | (hasO ? (gO & 0xFFFFu) : 0xFFFFu);
      if (hasO && nspE < MS) tev[nspE] = tsE2;
    }
    nsp = nspE + (hasO ? 1 : 0);

    // ---- L: issue w loads (consumed next pair) ----
    float wEn[4] = {0,0,0,0}, wOn[4] = {0,0,0,0};
    if (hasE) {
      float4 x = *(const float4*)&w[((size_t)gE << 11) + nb];
      wEn[0]=x.x; wEn[1]=x.y; wEn[2]=x.z; wEn[3]=x.w;
    }
    if (hasO) {
      float4 x = *(const float4*)&w[((size_t)gO << 11) + nb];
      wOn[0]=x.x; wOn[1]=x.y; wOn[2]=x.z; wOn[3]=x.w;
    }

    // ---- M: rotate carries ----
#pragma unroll
    for (int q = 0; q < 4; ++q) {
      vvO[q] = vvOn[q];
      ssE[q] = ssEn[q];
      evO[q] = evOn[q];
      y1iP[q] = y1iE[q];
      wEp[q] = wEn[q];
      wOp[q] = wOn[q];
      srE[q] = srEn[q];
      srO[q] = srOn[q];
    }
    hasEp = hasE; hasOp = hasO;
    dtOp = dtO;
    tsE = tsE2;
  }

  // ---- epilogue: leftover last step (T-1 odd) ----
  if ((T - 1) & 1) {
    const int e = T - 2;
    float vvE[4], iiE[4];
#pragma unroll
    for (int q = 0; q < 4; ++q) {
      float iiO = hasEp ? (y1iP[q] + wEp[q]) : y1iP[q];
      float dv  = m0 * ((iiO + icv[q]) - vvO[q]);
      float y1v = vvO[q] + dtOp * dv;
      float y1i = iiO + dtOp * ((-m1) * iiO);
      vvE[q] = y1v - (evO[q] ? 1.0f : 0.0f);
      iiE[q] = hasOp ? (y1i + wOp[q]) : y1i;
    }
    if (e == next_ck) {
      float* yr = ys + ((size_t)e * N_NEUR + nb) * 3;
      ((float4*)yr)[0] = make_float4(vvE[0], iiE[0], ssE[0], vvE[1]);
      ((float4*)yr)[1] = make_float4(iiE[1], ssE[1], vvE[2], iiE[2]);
      ((float4*)yr)[2] = make_float4(ssE[2], vvE[3], iiE[3], ssE[3]);
    }
    const float tsE1 = ts[T - 1];
    const float dtE = tsE1 - tsE;
    bool evE[4];
#pragma unroll
    for (int q = 0; q < 4; ++q) {
      float sp  = softplus_xla(vvE[q]);
      float y1s = ssE[q] + dtE * sp;
      evE[q] = (y1s >= 0.0f);
    }
    int lE = 4;
    if (evE[3]) lE = 3;
    if (evE[2]) lE = 2;
    if (evE[1]) lE = 1;
    if (evE[0]) lE = 0;
    unsigned long long bE = __ballot(lE < 4);
    if (lane == 0) {
      uint32_t cE = 0xFFFFFFFFu;
      if (bE) cE = (uint32_t)__builtin_amdgcn_readlane(nb + lE, __builtin_ctzll(bE));
      *(uint64_t*)&slot[pairs & 1][wave * 2] =
          ((uint64_t)0xFFFFFFFFu << 32) | (uint64_t)cE;
    }
    __syncthreads();
    uint32_t gE;
    {
      const uint4* rp = (const uint4*)&slot[pairs & 1][0];
      uint4 r0 = rp[0], r1 = rp[1], r2 = rp[2], r3 = rp[3];
      uint32_t a = r0.x < r1.x ? r0.x : r1.x;
      uint32_t b = r2.x < r3.x ? r2.x : r3.x;
      uint32_t c = r0.z < r1.z ? r0.z : r1.z;
      uint32_t d = r2.z < r3.z ? r2.z : r3.z;
      a = a < b ? a : b;  c = c < d ? c : d;
      gE = a < c ? a : c;
    }
    gE = (uint32_t)__builtin_amdgcn_readfirstlane((int)gE);
    const bool hasE = (gE != 0xFFFFFFFFu);
    if (tid == 0) {
      spk[e] = ((uint32_t)nsp << 16) | (hasE ? (gE & 0xFFFFu) : 0xFFFFu);
      if (hasE && nsp < MS) tev[nsp] = tsE1;
    }
    nsp += hasE ? 1 : 0;
  }

  if (tid == 0) nspp[0] = (float)nsp;
}

// ============ PHASE B: parallel replay (segments x 2 halves, 1 n/t) ===========
__global__ __launch_bounds__(1024, 1)
void snn_rep(const float* __restrict__ ts, const float* __restrict__ ic,
             const float* __restrict__ w, const float* __restrict__ mu,
             const float* __restrict__ sres, const uint32_t* __restrict__ spk,
             float* __restrict__ out, int T, int MS) {
#pragma clang fp contract(off)
  const int seg = blockIdx.x >> 1;
  const int gn = (blockIdx.x & 1) * 1024 + threadIdx.x;
  const int lo = seg * CKPT;
  const int end = min(lo + CKPT, T - 1);

  float* ys  = out;                                      // [T][N][3]
  float* tev = out + (size_t)T * N_NEUR * 3;
  float* yev = tev + (size_t)MS;                         // [MS][N][3]
  float* etv = yev + (size_t)MS * N_NEUR * 3;            // [MS][N]

  const float* y0r = ys + ((size_t)lo * N_NEUR + gn) * 3;
  float vv = y0r[0];
  float ii = y0r[1];
  float ss = y0r[2];
  const float icv = ic[gn];
  const float m0 = mu[0], m1 = mu[1];
  float tp = ts[lo];

  for (int k = lo; k < end; ++k) {
    const float tn = ts[k + 1];
    const float dt = tn - tp;
    tp = tn;
    const uint32_t pk = spk[k];

    float sp  = softplus_xla(vv);
    float y1s = ss + dt * sp;
    const bool ev = (y1s >= 0.0f);
    float dv  = m0 * ((ii + icv) - vv);
    float y1v = vv + dt * dv;
    float y1i = ii + dt * ((-m1) * ii);

    const uint32_t e16 = pk & 0xFFFFu;
    const bool has = (e16 != 0xFFFFu);
    const uint32_t nsp = pk >> 16;

    float wv = 0.0f;
    if (has) wv = w[((size_t)e16 << 11) + gn];

    if (has && nsp < (uint32_t)MS) {
      float* ye = yev + ((size_t)nsp * N_NEUR + gn) * 3;
      ye[0] = y1v; ye[1] = y1i; ye[2] = y1s;
      etv[(size_t)nsp * N_NEUR + gn] = ev ? 1.0f : 0.0f;
    }

    ii = has ? (y1i + wv) : y1i;
    vv = y1v - (ev ? 1.0f : 0.0f);
    if (ev) ss = sres[(size_t)k * N_NEUR + gn]; else ss = y1s;

    float* yr = ys + ((size_t)(k + 1) * N_NEUR + gn) * 3;
    yr[0] = vv; yr[1] = ii; yr[2] = ss;
  }
}

// ============ FALLBACK: single-kernel scan (if workspace too small) ===========
template <bool USE_SRES>
__global__ __launch_bounds__(1024, 1)
void snn_sim(const float* __restrict__ ts, const float* __restrict__ v0,
             const float* __restrict__ i0, const float* __restrict__ ic,
             const float* __restrict__ w, const float* __restrict__ mu,
             const int* __restrict__ seedp, const float* __restrict__ sres,
             float* __restrict__ out, int T, int MS) {
#pragma clang fp contract(off)
  const int tid = threadIdx.x;
  const int nb = tid * 2;
  const int lane = tid & 63;

  float* ys   = out;
  float* tev  = out + (size_t)T * N_NEUR * 3;
  float* yev  = tev + (size_t)MS;
  float* etv  = yev + (size_t)MS * N_NEUR * 3;
  float* nspp = etv + (size_t)MS * N_NEUR;

  uint32_t seed = (uint32_t)seedp[0];
  uint32_t a0 = 0u, a1 = 2u; tf2x32(0u, seed, a0, a1);
  uint32_t b0 = 1u, b1 = 3u; tf2x32(0u, seed, b0, b1);
  const uint32_t ki0 = a0, ki1 = b0;
  const uint32_t kt0 = a1, kt1 = b1;

  float vv0, vv1, ii0, ii1, ss0, ss1, icv0, icv1;
  { float2 x = *(const float2*)&v0[nb]; vv0 = x.x; vv1 = x.y; }
  { float2 x = *(const float2*)&i0[nb]; ii0 = x.x; ii1 = x.y; }
  { float2 x = *(const float2*)&ic[nb]; icv0 = x.x; icv1 = x.y; }
  {
    uint32_t c0 = (uint32_t)(nb < HALF_N ? nb : nb - HALF_N);
    uint32_t c1 = c0 + HALF_N;
    tf2x32(ki0, ki1, c0, c1);
    ss0 = xla_log(u01_from_bits(nb < HALF_N ? c0 : c1)) - 0.01f;
  }
  {
    int j = nb + 1;
    uint32_t c0 = (uint32_t)(j < HALF_N ? j : j - HALF_N);
    uint32_t c1 = c0 + HALF_N;
    tf2x32(ki0, ki1, c0, c1);
    ss1 = xla_log(u01_from_bits(j < HALF_N ? c0 : c1)) - 0.01f;
  }
  const float m0 = mu[0], m1 = mu[1];

  {
    float* yr = ys + (size_t)nb * 3;
    ((float2*)yr)[0] = make_float2(vv0, ii0);
    ((float2*)yr)[1] = make_float2(ss0, vv1);
    ((float2*)yr)[2] = make_float2(ii1, ss1);
  }

  __shared__ uint32_t slot[4];
  if (tid < 4) slot[tid] = 0xFFFFFFFFu;
  __syncthreads();

  int nsp = 0;
  float tp = ts[0];
  const float* srp = USE_SRES ? (sres + nb) : nullptr;
  float* yrow = ys + (size_t)N_NEUR * 3 + (size_t)nb * 3;

  for (int k = 0; k < T - 1; ++k) {
    const float tn = ts[k + 1];
    const float dt = tn - tp;
    tp = tn;

    float sr0 = 0.0f, sr1 = 0.0f;
    if (USE_SRES) {
      float2 x = *(const float2*)srp;
      sr0 = x.x; sr1 = x.y;
      srp += N_NEUR;
    }

    float sp0 = softplus_xla(vv0);
    float sp1 = softplus_xla(vv1);
    float y1s0 = ss0 + dt * sp0;
    float y1s1 = ss1 + dt * sp1;
    const bool ev0 = (y1s0 >= 0.0f);
    const bool ev1 = (y1s1 >= 0.0f);

    int lidx = ev0 ? 0 : (ev1 ? 1 : 2);
    unsigned long long bm = __ballot(lidx < 2);
    if (lane == 0 && bm) {
      int fl = __builtin_ctzll(bm);
      uint32_t cand = (uint32_t)__builtin_amdgcn_readlane(nb + lidx, fl);
      atomicMin(&slot[k & 3], cand);
    }
    if (tid == 0) slot[(k + 1) & 3] = 0xFFFFFFFFu;

    float dv0 = m0 * ((ii0 + icv0) - vv0);
    float dv1 = m0 * ((ii1 + icv1) - vv1);
    float y1v0 = vv0 + dt * dv0;
    float y1v1 = vv1 + dt * dv1;
    float y1i0 = ii0 + dt * ((-m1) * ii0);
    float y1i1 = ii1 + dt * ((-m1) * ii1);

    __syncthreads();

    uint32_t gmin = (uint32_t)__builtin_amdgcn_readfirstlane((int)slot[k & 3]);
    const bool has = (gmin != 0xFFFFFFFFu);

    float wv0 = 0.0f, wv1 = 0.0f;
    if (has) {
      float2 x = *(const float2*)&w[((size_t)gmin << 11) + nb];
      wv0 = x.x; wv1 = x.y;
    }

    if (has && nsp < MS) {
      if (tid == 0) tev[nsp] = tn;
      float* ye = yev + ((size_t)nsp * N_NEUR + nb) * 3;
      ((float2*)ye)[0] = make_float2(y1v0, y1i0);
      ((float2*)ye)[1] = make_float2(y1s0, y1v1);
      ((float2*)ye)[2] = make_float2(y1i1, y1s1);
      *(float2*)(etv + (size_t)nsp * N_NEUR + nb) =
          make_float2(ev0 ? 1.0f : 0.0f, ev1 ? 1.0f : 0.0f);
    }
    nsp += has ? 1 : 0;

    ii0 = has ? (y1i0 + wv0) : y1i0;
    ii1 = has ? (y1i1 + wv1) : y1i1;
    vv0 = y1v0 - (ev0 ? 1.0f : 0.0f);
    vv1 = y1v1 - (ev1 ? 1.0f : 0.0f);
    if (USE_SRES) {
      ss0 = ev0 ? sr0 : y1s0;
      ss1 = ev1 ? sr1 : y1s1;
    } else {
      ss0 = y1s0; ss1 = y1s1;
      if (ev0 | ev1) {
        uint32_t f0 = 0u, f1 = (uint32_t)k;
        tf2x32(kt0, kt1, f0, f1);
        if (ev0) {
          uint32_t c0 = (uint32_t)(nb < HALF_N ? nb : nb - HALF_N);
          uint32_t c1 = c0 + HALF_N;
          tf2x32(f0, f1, c0, c1);
          ss0 = xla_log(u01_from_bits(nb < HALF_N ? c0 : c1)) - 0.01f;
        }
        if (ev1) {
          int j = nb + 1;
          uint32_t c0 = (uint32_t)(j < HALF_N ? j : j - HALF_N);
          uint32_t c1 = c0 + HALF_N;
          tf2x32(f0, f1, c0, c1);
          ss1 = xla_log(u01_from_bits(j < HALF_N ? c0 : c1)) - 0.01f;
        }
      }
    }

    ((float2*)yrow)[0] = make_float2(vv0, ii0);
    ((float2*)yrow)[1] = make_float2(ss0, vv1);
    ((float2*)yrow)[2] = make_float2(ii1, ss1);
    yrow += (size_t)N_NEUR * 3;
  }

  if (tid == 0) nspp[0] = (float)nsp;
}

extern "C" void kernel_launch(void* const* d_in, const int* in_sizes, int n_in,
                              void* d_out, int out_size, void* d_ws, size_t ws_size,
                              hipStream_t stream) {
  const float* ts = (const float*)d_in[0];
  const float* v0 = (const float*)d_in[1];
  const float* i0 = (const float*)d_in[2];
  const float* ic = (const float*)d_in[3];
  const float* w  = (const float*)d_in[4];
  const float* mu = (const float*)d_in[5];
  const int* seed = (const int*)d_in[6];

  const int T = in_sizes[0];      // 4000
  const int N = in_sizes[1];      // 2048
  long long rem = (long long)out_size - (long long)T * N * 3 - 1;
  int MS = (int)(rem / (1 + 4 * (long long)N));
  if (MS <= 0) MS = 512;

  size_t inf_base = (size_t)T * N * 3;
  size_t inf_cnt  = (size_t)MS + (size_t)MS * N * 3;
  size_t zero_cnt = (size_t)MS * N;
  snn_init<<<dim3(512), dim3(256), 0, stream>>>((float*)d_out, inf_base, inf_cnt, zero_cnt);

  // ws layout: [0, sres_bytes) = sres; [sres_bytes, +4*(T-1)) = spk
  size_t sres_bytes = (size_t)(T - 1) * (size_t)N * sizeof(float);
  size_t full_bytes = sres_bytes + (size_t)(T - 1) * sizeof(uint32_t);

  if (ws_size >= full_bytes) {
    float* sres = (float*)d_ws;
    uint32_t* spk = (uint32_t*)((char*)d_ws + sres_bytes);
    snn_pre<<<dim3(T - 1), dim3(1024), 0, stream>>>(seed, sres);
    snn_evt<<<dim3(1), dim3(512), 0, stream>>>(ts, v0, i0, ic, w, mu, seed,
                                               sres, spk, (float*)d_out, T, MS);
    int nseg = (T - 1 + CKPT - 1) / CKPT;
    snn_rep<<<dim3(nseg * 2), dim3(1024), 0, stream>>>(ts, ic, w, mu, sres, spk,
                                                       (float*)d_out, T, MS);
  } else if (ws_size >= sres_bytes) {
    snn_pre<<<dim3(T - 1), dim3(1024), 0, stream>>>(seed, (float*)d_ws);
    snn_sim<true><<<dim3(1), dim3(1024), 0, stream>>>(ts, v0, i0, ic, w, mu, seed,
                                                      (const float*)d_ws,
                                                      (float*)d_out, T, MS);
  } else {
    snn_sim<false><<<dim3(1), dim3(1024), 0, stream>>>(ts, v0, i0, ic, w, mu, seed,
                                                       nullptr, (float*)d_out, T, MS);
  }
}

// Round 10
// 2978.256 us; speedup vs baseline: 1.1422x; 1.0399x over previous
//
#include <hip/hip_runtime.h>
#include <stdint.h>

// ====== variant switches for XLA:CPU transcendental reconstruction ======
// (verified bit-exact in round 1 — DO NOT change the math)
#define XLA_LOG_TAIL_A 1
#define XLA_USE_FMA    0

#if XLA_USE_FMA
#define MADD(a,b,c) __builtin_fmaf((a),(b),(c))
#else
#define MADD(a,b,c) ((a)*(b)+(c))
#endif

#define N_NEUR 2048
#define HALF_N 1024
#define CKPT   124      // even: checkpoints land on even (pair-start) steps

// ---------------- threefry2x32 (exact JAX primitive) ----------------
__device__ __forceinline__ uint32_t rotl32(uint32_t x, int r) {
  return (x << r) | (x >> (32 - r));
}

__device__ __forceinline__ void tf2x32(uint32_t k0, uint32_t k1,
                                       uint32_t& x0, uint32_t& x1) {
  const uint32_t k2 = k0 ^ k1 ^ 0x1BD11BDAu;
  x0 += k0; x1 += k1;
#define TF_R(r) { x0 += x1; x1 = rotl32(x1, r); x1 ^= x0; }
  TF_R(13) TF_R(15) TF_R(26) TF_R(6)
  x0 += k1; x1 += k2 + 1u;
  TF_R(17) TF_R(29) TF_R(16) TF_R(24)
  x0 += k2; x1 += k0 + 2u;
  TF_R(13) TF_R(15) TF_R(26) TF_R(6)
  x0 += k0; x1 += k1 + 3u;
  TF_R(17) TF_R(29) TF_R(16) TF_R(24)
  x0 += k1; x1 += k2 + 4u;
  TF_R(13) TF_R(15) TF_R(26) TF_R(6)
  x0 += k2; x1 += k0 + 5u;
#undef TF_R
}

__device__ __forceinline__ float u01_from_bits(uint32_t bits) {
#pragma clang fp contract(off)
  float f = __uint_as_float((bits >> 9) | 0x3f800000u);
  return f - 1.0f;
}

// ---------------- XLA:CPU GenerateVF32Log (Cephes, Estrin poly) ----------------
__device__ __forceinline__ float xla_log(float xin) {
#pragma clang fp contract(off)
  float t0 = fmaxf(xin, __uint_as_float(0x00800000u));
  uint32_t bits = __float_as_uint(t0);
  int em = (int)(bits >> 23) - 127;
  t0 = __uint_as_float((bits & 0x807fffffu) | 0x3f000000u);
  float e = 1.0f + (float)em;
  const bool mlt = t0 < (float)0.707106781186547524;
  float tmp1 = mlt ? t0 : 0.0f;
  t0 = t0 - 1.0f;
  e = e - (mlt ? 1.0f : 0.0f);
  t0 = t0 + tmp1;
  float x2 = t0 * t0;
  float x3 = x2 * t0;
  float y  = MADD(t0, (float)7.0376836292E-2, (float)-1.1514610310E-1);
  float ya = MADD(t0, (float)-1.2420140846E-1, (float)1.4249322787E-1);
  float yb = MADD(t0, (float)2.0000714765E-1, (float)-2.4999993993E-1);
  y  = MADD(y,  t0, (float)1.1676998740E-1);
  ya = MADD(ya, t0, (float)-1.6668057665E-1);
  yb = MADD(yb, t0, (float)3.3333331174E-1);
  y  = MADD(y, x3, ya);
  y  = MADD(y, x3, yb);
  y  = y * x3;
  float ey1 = e * (float)-2.12194440e-4;
  float hx2 = x2 * 0.5f;
  y = y + ey1;
  t0 = t0 - hx2;
  float ey2 = e * (float)0.693359375;
#if XLA_LOG_TAIL_A
  t0 = t0 + y;
  t0 = t0 + ey2;
#else
  t0 = t0 + ey2;
  t0 = t0 + y;
#endif
  if (xin == 0.0f) return -__builtin_inff();
  return t0;
}

// ---------------- XLA:CPU GenerateVF32Exp (old Cephes structure) ----------------
__device__ __forceinline__ float xla_exp(float xin) {
#pragma clang fp contract(off)
  float x = fmaxf(xin, (float)-88.3762626647949);
  x = fminf(x, (float)88.3762626647950);
  float fx = floorf(MADD(x, (float)1.44269504088896341, 0.5f));
  float tmp = (float)0.693359375 * fx;
  float z = (float)-2.12194440e-4 * fx;
  x = x - tmp;
  x = x - z;
  z = x * x;
  float y = MADD(x, (float)1.9875691500E-4, (float)1.3981999507E-3);
  y = MADD(y, x, (float)8.3334519073E-3);
  y = MADD(y, x, (float)4.1665795894E-2);
  y = MADD(y, x, (float)1.6666665459E-1);
  y = MADD(y, x, (float)5.0000001201E-1);
  y = MADD(y, z, x);
  y = 1.0f + y;
  int n = (int)fx;
  float p2n = __uint_as_float((uint32_t)(n + 127) << 23);
  return fmaxf(y * p2n, xin);
}

__device__ __forceinline__ float xla_log1p(float x) {
#pragma clang fp contract(off)
  float fl = xla_log(x + 1.0f);
  float fs = ((-0.5f * x) + 1.0f) * x;
  return (fabsf(x) < (float)1e-4) ? fs : fl;
}

// jax.nn.softplus(v) = max(v,0) + log1p(exp(-|v|))
__device__ __forceinline__ float softplus_xla(float v) {
#pragma clang fp contract(off)
  // exact shortcut: for v>=16, exp(-v)<=1.13e-7 < ulp(v)/2 -> sum rounds to v
  if (v >= 16.0f) return v;
  float a = fabsf(v);
  float ex = xla_exp(-a);
  float lp = xla_log1p(ex);
  return fmaxf(v, 0.0f) + lp;
}

// ---------------- init: tevents/yevents = +inf, event_types = 0 ----------------
__global__ void snn_init(float* __restrict__ out, size_t inf_base,
                         size_t inf_cnt, size_t zero_cnt) {
  size_t i = (size_t)blockIdx.x * blockDim.x + threadIdx.x;
  size_t stride = (size_t)gridDim.x * blockDim.x;
  size_t total = inf_cnt + zero_cnt;
  for (size_t k = i; k < total; k += stride) {
    out[inf_base + k] = (k < inf_cnt) ? __builtin_inff() : 0.0f;
  }
}

// ---------------- precompute s_reset[step][j] = log(u)-alpha into sres ---------
__global__ __launch_bounds__(1024)
void snn_pre(const int* __restrict__ seedp, float* __restrict__ sres) {
#pragma clang fp contract(off)
  const int step = blockIdx.x;       // 0..T-2
  const int t = threadIdx.x;
  uint32_t seed = (uint32_t)seedp[0];
  uint32_t a0 = 0u, a1 = 2u; tf2x32(0u, seed, a0, a1);
  uint32_t b0 = 1u, b1 = 3u; tf2x32(0u, seed, b0, b1);
  uint32_t f0 = 0u, f1 = (uint32_t)step; tf2x32(a1, b1, f0, f1);
  uint32_t d0 = (uint32_t)t, d1 = (uint32_t)(t + HALF_N);
  tf2x32(f0, f1, d0, d1);
  float srA = xla_log(u01_from_bits(d0)) - 0.01f;
  float srB = xla_log(u01_from_bits(d1)) - 0.01f;
  sres[(size_t)step * N_NEUR + t] = srA;
  sres[(size_t)step * N_NEUR + HALF_N + t] = srB;
}

// ============ PHASE A: decision chain, 2 steps/barrier, 16 waves ==============
// 1024 thr x 2 contiguous neurons. Reduce: per-wave ballot -> lane0 atomicMin
// into slot[P&3][E/O] (4-deep parity rotation, reset 2 pairs ahead); one
// barrier/pair; post-barrier: one 8B broadcast read + readfirstlane.
__global__ __launch_bounds__(1024, 1)
void snn_evt(const float* __restrict__ ts, const float* __restrict__ v0,
             const float* __restrict__ i0, const float* __restrict__ ic,
             const float* __restrict__ w, const float* __restrict__ mu,
             const int* __restrict__ seedp, const float* __restrict__ sres,
             uint32_t* __restrict__ spk, float* __restrict__ out, int T, int MS) {
#pragma clang fp contract(off)
  const int tid = threadIdx.x;
  const int nb = tid * 2;               // neurons nb, nb+1
  const int lane = tid & 63;

  float* ys   = out;                                     // [T][N][3]
  float* tev  = out + (size_t)T * N_NEUR * 3;            // [MS]
  float* etv  = tev + (size_t)MS + (size_t)MS * N_NEUR * 3;
  float* nspp = etv + (size_t)MS * N_NEUR;               // [1]

  // keys
  uint32_t seed = (uint32_t)seedp[0];
  uint32_t a0 = 0u, a1 = 2u; tf2x32(0u, seed, a0, a1);
  uint32_t b0 = 1u, b1 = 3u; tf2x32(0u, seed, b0, b1);
  const uint32_t ki0 = a0, ki1 = b0;

  const float m0 = mu[0], m1 = mu[1];

  // carried state (E = even step committed, O = odd step)
  float vvO[2], ssE[2], y1iP[2], wEp[2], wOp[2], icv[2], srE[2], srO[2];
  bool  evO[2];
  bool  hasEp = false, hasOp = false;
  float dtOp = 0.0f;   // 0 => prologue zero-dt trick

  { float2 x = *(const float2*)&v0[nb]; vvO[0]=x.x; vvO[1]=x.y; }
  { float2 x = *(const float2*)&i0[nb]; y1iP[0]=x.x; y1iP[1]=x.y; }
  { float2 x = *(const float2*)&ic[nb]; icv[0]=x.x; icv[1]=x.y; }
#pragma unroll
  for (int q = 0; q < 2; ++q) {
    int j = nb + q;
    uint32_t c0 = (uint32_t)(j < HALF_N ? j : j - HALF_N);
    uint32_t c1 = c0 + HALF_N;
    tf2x32(ki0, ki1, c0, c1);
    ssE[q] = xla_log(u01_from_bits(j < HALF_N ? c0 : c1)) - 0.01f;
    evO[q] = false;
    wEp[q] = 0.0f; wOp[q] = 0.0f;
  }
  { float2 x = *(const float2*)(sres + nb);          srE[0]=x.x; srE[1]=x.y; }
  { float2 x = *(const float2*)(sres + N_NEUR + nb); srO[0]=x.x; srO[1]=x.y; }

  __shared__ alignas(8) uint32_t slot[4][2];   // [pair&3][E/O]
  if (tid < 8) ((uint32_t*)slot)[tid] = 0xFFFFFFFFu;
  __syncthreads();

  int nsp = 0;
  int next_ck = 0;
  float tsE = ts[0];
  const int pairs = (T - 1) >> 1;
  const int last_row = T - 2;

  for (int P = 0; P < pairs; ++P) {
    const int e = 2 * P;

    // ---- early issues: ts, next-pair sres, slot reset (covers in-flight w) ----
    const float tsE1 = ts[e + 1];
    const float tsE2 = ts[e + 2];
    float srEn[2], srOn[2];
    {
      int re = e + 2;  if (re > last_row) re = last_row;
      int ro = e + 3;  if (ro > last_row) ro = last_row;
      float2 x = *(const float2*)(sres + (size_t)re * N_NEUR + nb);
      srEn[0]=x.x; srEn[1]=x.y;
      float2 y = *(const float2*)(sres + (size_t)ro * N_NEUR + nb);
      srOn[0]=y.x; srOn[1]=y.y;
    }
    if (tid == 0) {
      slot[(P + 2) & 3][0] = 0xFFFFFFFFu;
      slot[(P + 2) & 3][1] = 0xFFFFFFFFu;
    }

    // ---- A: finish deferred step o_prev (consumes w loaded last pair) ----
    float vvE[2], iiE[2], y1iO_[2];
#pragma unroll
    for (int q = 0; q < 2; ++q) {
      float iiO = hasEp ? (y1iP[q] + wEp[q]) : y1iP[q];
      float dv  = m0 * ((iiO + icv[q]) - vvO[q]);
      float y1v = vvO[q] + dtOp * dv;
      float y1i = iiO + dtOp * ((-m1) * iiO);
      vvE[q] = y1v - (evO[q] ? 1.0f : 0.0f);
      y1iO_[q] = y1i;
    }
#pragma unroll
    for (int q = 0; q < 2; ++q)
      iiE[q] = hasOp ? (y1iO_[q] + wOp[q]) : y1iO_[q];

    // ---- checkpoint (rare, uniform) ----
    if (e == next_ck) {
      float* yr = ys + ((size_t)e * N_NEUR + nb) * 3;
      ((float2*)yr)[0] = make_float2(vvE[0], iiE[0]);
      ((float2*)yr)[1] = make_float2(ssE[0], vvE[1]);
      ((float2*)yr)[2] = make_float2(iiE[1], ssE[1]);
      next_ck += CKPT;
    }

    const float dtE = tsE1 - tsE;
    const float dtO = tsE2 - tsE1;

    // ---- two event steps, lane-local (expressions verbatim) ----
    float y1iE[2], vvOn[2], ssEn[2];
    bool evE[2], evOn[2];
#pragma unroll
    for (int q = 0; q < 2; ++q) {
      float sp  = softplus_xla(vvE[q]);
      float y1s = ssE[q] + dtE * sp;
      evE[q] = (y1s >= 0.0f);
      float dv  = m0 * ((iiE[q] + icv[q]) - vvE[q]);
      float y1v = vvE[q] + dtE * dv;
      y1iE[q] = iiE[q] + dtE * ((-m1) * iiE[q]);
      vvOn[q] = y1v - (evE[q] ? 1.0f : 0.0f);
      float ssO_ = evE[q] ? srE[q] : y1s;
      float spO = softplus_xla(vvOn[q]);
      float y1sO = ssO_ + dtO * spO;
      evOn[q] = (y1sO >= 0.0f);
      ssEn[q] = evOn[q] ? srO[q] : y1sO;
    }

    // ---- candidates: ballot -> lane0 atomicMin ----
    {
      int lE = evE[0] ? 0 : (evE[1] ? 1 : 2);
      int lO = evOn[0] ? 0 : (evOn[1] ? 1 : 2);
      unsigned long long bE = __ballot(lE < 2);
      unsigned long long bO = __ballot(lO < 2);
      if (lane == 0) {
        if (bE) {
          uint32_t cE = (uint32_t)__builtin_amdgcn_readlane(nb + lE, __builtin_ctzll(bE));
          atomicMin(&slot[P & 3][0], cE);
        }
        if (bO) {
          uint32_t cO = (uint32_t)__builtin_amdgcn_readlane(nb + lO, __builtin_ctzll(bO));
          atomicMin(&slot[P & 3][1], cO);
        }
      }
    }

    __syncthreads();

    // ---- combined minima (8B broadcast read) ----
    uint2 rr = *(const uint2*)&slot[P & 3][0];
    uint32_t gE = (uint32_t)__builtin_amdgcn_readfirstlane((int)rr.x);
    uint32_t gO = (uint32_t)__builtin_amdgcn_readfirstlane((int)rr.y);
    const bool hasE = (gE != 0xFFFFFFFFu);
    const bool hasO = (gO != 0xFFFFFFFFu);

    // ---- bookkeeping (tid0) ----
    if (tid == 0) {
      spk[e] = ((uint32_t)nsp << 16) | (hasE ? (gE & 0xFFFFu) : 0xFFFFu);
      if (hasE && nsp < MS) tev[nsp] = tsE1;
    }
    int nspE = nsp + (hasE ? 1 : 0);
    if (tid == 0) {
      spk[e + 1] = ((uint32_t)nspE << 16) | (hasO ? (gO & 0xFFFFu) : 0xFFFFu);
      if (hasO && nspE < MS) tev[nspE] = tsE2;
    }
    nsp = nspE + (hasO ? 1 : 0);

    // ---- issue w loads (consumed next pair) ----
    float wEn[2] = {0, 0}, wOn[2] = {0, 0};
    if (hasE) {
      float2 x = *(const float2*)&w[((size_t)gE << 11) + nb];
      wEn[0]=x.x; wEn[1]=x.y;
    }
    if (hasO) {
      float2 x = *(const float2*)&w[((size_t)gO << 11) + nb];
      wOn[0]=x.x; wOn[1]=x.y;
    }

    // ---- rotate carries ----
#pragma unroll
    for (int q = 0; q < 2; ++q) {
      vvO[q] = vvOn[q];
      ssE[q] = ssEn[q];
      evO[q] = evOn[q];
      y1iP[q] = y1iE[q];
      wEp[q] = wEn[q];
      wOp[q] = wOn[q];
      srE[q] = srEn[q];
      srO[q] = srOn[q];
    }
    hasEp = hasE; hasOp = hasO;
    dtOp = dtO;
    tsE = tsE2;
  }

  // ---- epilogue: leftover last step (T-1 odd) ----
  if ((T - 1) & 1) {
    const int e = T - 2;
    float vvE[2], iiE[2];
#pragma unroll
    for (int q = 0; q < 2; ++q) {
      float iiO = hasEp ? (y1iP[q] + wEp[q]) : y1iP[q];
      float dv  = m0 * ((iiO + icv[q]) - vvO[q]);
      float y1v = vvO[q] + dtOp * dv;
      float y1i = iiO + dtOp * ((-m1) * iiO);
      vvE[q] = y1v - (evO[q] ? 1.0f : 0.0f);
      iiE[q] = hasOp ? (y1i + wOp[q]) : y1i;
    }
    if (e == next_ck) {
      float* yr = ys + ((size_t)e * N_NEUR + nb) * 3;
      ((float2*)yr)[0] = make_float2(vvE[0], iiE[0]);
      ((float2*)yr)[1] = make_float2(ssE[0], vvE[1]);
      ((float2*)yr)[2] = make_float2(iiE[1], ssE[1]);
    }
    const float tsE1 = ts[T - 1];
    const float dtE = tsE1 - tsE;
    bool evE[2];
#pragma unroll
    for (int q = 0; q < 2; ++q) {
      float sp  = softplus_xla(vvE[q]);
      float y1s = ssE[q] + dtE * sp;
      evE[q] = (y1s >= 0.0f);
    }
    int lE = evE[0] ? 0 : (evE[1] ? 1 : 2);
    unsigned long long bE = __ballot(lE < 2);
    if (lane == 0 && bE) {
      uint32_t cE = (uint32_t)__builtin_amdgcn_readlane(nb + lE, __builtin_ctzll(bE));
      atomicMin(&slot[pairs & 3][0], cE);
    }
    __syncthreads();
    uint32_t gE = (uint32_t)__builtin_amdgcn_readfirstlane((int)slot[pairs & 3][0]);
    const bool hasE = (gE != 0xFFFFFFFFu);
    if (tid == 0) {
      spk[e] = ((uint32_t)nsp << 16) | (hasE ? (gE & 0xFFFFu) : 0xFFFFu);
      if (hasE && nsp < MS) tev[nsp] = tsE1;
    }
    nsp += hasE ? 1 : 0;
  }

  if (tid == 0) nspp[0] = (float)nsp;
}

// ============ PHASE B: parallel replay (segments x 2 halves, 1 n/t) ===========
__global__ __launch_bounds__(1024, 1)
void snn_rep(const float* __restrict__ ts, const float* __restrict__ ic,
             const float* __restrict__ w, const float* __restrict__ mu,
             const float* __restrict__ sres, const uint32_t* __restrict__ spk,
             float* __restrict__ out, int T, int MS) {
#pragma clang fp contract(off)
  const int seg = blockIdx.x >> 1;
  const int gn = (blockIdx.x & 1) * 1024 + threadIdx.x;
  const int lo = seg * CKPT;
  const int end = min(lo + CKPT, T - 1);

  float* ys  = out;                                      // [T][N][3]
  float* tev = out + (size_t)T * N_NEUR * 3;
  float* yev = tev + (size_t)MS;                         // [MS][N][3]
  float* etv = yev + (size_t)MS * N_NEUR * 3;            // [MS][N]

  const float* y0r = ys + ((size_t)lo * N_NEUR + gn) * 3;
  float vv = y0r[0];
  float ii = y0r[1];
  float ss = y0r[2];
  const float icv = ic[gn];
  const float m0 = mu[0], m1 = mu[1];
  float tp = ts[lo];

  for (int k = lo; k < end; ++k) {
    const float tn = ts[k + 1];
    const float dt = tn - tp;
    tp = tn;
    const uint32_t pk = spk[k];

    float sp  = softplus_xla(vv);
    float y1s = ss + dt * sp;
    const bool ev = (y1s >= 0.0f);
    float dv  = m0 * ((ii + icv) - vv);
    float y1v = vv + dt * dv;
    float y1i = ii + dt * ((-m1) * ii);

    const uint32_t e16 = pk & 0xFFFFu;
    const bool has = (e16 != 0xFFFFu);
    const uint32_t nsp = pk >> 16;

    float wv = 0.0f;
    if (has) wv = w[((size_t)e16 << 11) + gn];

    if (has && nsp < (uint32_t)MS) {
      float* ye = yev + ((size_t)nsp * N_NEUR + gn) * 3;
      ye[0] = y1v; ye[1] = y1i; ye[2] = y1s;
      etv[(size_t)nsp * N_NEUR + gn] = ev ? 1.0f : 0.0f;
    }

    ii = has ? (y1i + wv) : y1i;
    vv = y1v - (ev ? 1.0f : 0.0f);
    if (ev) ss = sres[(size_t)k * N_NEUR + gn]; else ss = y1s;

    float* yr = ys + ((size_t)(k + 1) * N_NEUR + gn) * 3;
    yr[0] = vv; yr[1] = ii; yr[2] = ss;
  }
}

// ============ FALLBACK: single-kernel scan (if workspace too small) ===========
template <bool USE_SRES>
__global__ __launch_bounds__(1024, 1)
void snn_sim(const float* __restrict__ ts, const float* __restrict__ v0,
             const float* __restrict__ i0, const float* __restrict__ ic,
             const float* __restrict__ w, const float* __restrict__ mu,
             const int* __restrict__ seedp, const float* __restrict__ sres,
             float* __restrict__ out, int T, int MS) {
#pragma clang fp contract(off)
  const int tid = threadIdx.x;
  const int nb = tid * 2;
  const int lane = tid & 63;

  float* ys   = out;
  float* tev  = out + (size_t)T * N_NEUR * 3;
  float* yev  = tev + (size_t)MS;
  float* etv  = yev + (size_t)MS * N_NEUR * 3;
  float* nspp = etv + (size_t)MS * N_NEUR;

  uint32_t seed = (uint32_t)seedp[0];
  uint32_t a0 = 0u, a1 = 2u; tf2x32(0u, seed, a0, a1);
  uint32_t b0 = 1u, b1 = 3u; tf2x32(0u, seed, b0, b1);
  const uint32_t ki0 = a0, ki1 = b0;
  const uint32_t kt0 = a1, kt1 = b1;

  float vv0, vv1, ii0, ii1, ss0, ss1, icv0, icv1;
  { float2 x = *(const float2*)&v0[nb]; vv0 = x.x; vv1 = x.y; }
  { float2 x = *(const float2*)&i0[nb]; ii0 = x.x; ii1 = x.y; }
  { float2 x = *(const float2*)&ic[nb]; icv0 = x.x; icv1 = x.y; }
  {
    uint32_t c0 = (uint32_t)(nb < HALF_N ? nb : nb - HALF_N);
    uint32_t c1 = c0 + HALF_N;
    tf2x32(ki0, ki1, c0, c1);
    ss0 = xla_log(u01_from_bits(nb < HALF_N ? c0 : c1)) - 0.01f;
  }
  {
    int j = nb + 1;
    uint32_t c0 = (uint32_t)(j < HALF_N ? j : j - HALF_N);
    uint32_t c1 = c0 + HALF_N;
    tf2x32(ki0, ki1, c0, c1);
    ss1 = xla_log(u01_from_bits(j < HALF_N ? c0 : c1)) - 0.01f;
  }
  const float m0 = mu[0], m1 = mu[1];

  {
    float* yr = ys + (size_t)nb * 3;
    ((float2*)yr)[0] = make_float2(vv0, ii0);
    ((float2*)yr)[1] = make_float2(ss0, vv1);
    ((float2*)yr)[2] = make_float2(ii1, ss1);
  }

  __shared__ uint32_t slot[4];
  if (tid < 4) slot[tid] = 0xFFFFFFFFu;
  __syncthreads();

  int nsp = 0;
  float tp = ts[0];
  const float* srp = USE_SRES ? (sres + nb) : nullptr;
  float* yrow = ys + (size_t)N_NEUR * 3 + (size_t)nb * 3;

  for (int k = 0; k < T - 1; ++k) {
    const float tn = ts[k + 1];
    const float dt = tn - tp;
    tp = tn;

    float sr0 = 0.0f, sr1 = 0.0f;
    if (USE_SRES) {
      float2 x = *(const float2*)srp;
      sr0 = x.x; sr1 = x.y;
      srp += N_NEUR;
    }

    float sp0 = softplus_xla(vv0);
    float sp1 = softplus_xla(vv1);
    float y1s0 = ss0 + dt * sp0;
    float y1s1 = ss1 + dt * sp1;
    const bool ev0 = (y1s0 >= 0.0f);
    const bool ev1 = (y1s1 >= 0.0f);

    int lidx = ev0 ? 0 : (ev1 ? 1 : 2);
    unsigned long long bm = __ballot(lidx < 2);
    if (lane == 0 && bm) {
      int fl = __builtin_ctzll(bm);
      uint32_t cand = (uint32_t)__builtin_amdgcn_readlane(nb + lidx, fl);
      atomicMin(&slot[k & 3], cand);
    }
    if (tid == 0) slot[(k + 1) & 3] = 0xFFFFFFFFu;

    float dv0 = m0 * ((ii0 + icv0) - vv0);
    float dv1 = m0 * ((ii1 + icv1) - vv1);
    float y1v0 = vv0 + dt * dv0;
    float y1v1 = vv1 + dt * dv1;
    float y1i0 = ii0 + dt * ((-m1) * ii0);
    float y1i1 = ii1 + dt * ((-m1) * ii1);

    __syncthreads();

    uint32_t gmin = (uint32_t)__builtin_amdgcn_readfirstlane((int)slot[k & 3]);
    const bool has = (gmin != 0xFFFFFFFFu);

    float wv0 = 0.0f, wv1 = 0.0f;
    if (has) {
      float2 x = *(const float2*)&w[((size_t)gmin << 11) + nb];
      wv0 = x.x; wv1 = x.y;
    }

    if (has && nsp < MS) {
      if (tid == 0) tev[nsp] = tn;
      float* ye = yev + ((size_t)nsp * N_NEUR + nb) * 3;
      ((float2*)ye)[0] = make_float2(y1v0, y1i0);
      ((float2*)ye)[1] = make_float2(y1s0, y1v1);
      ((float2*)ye)[2] = make_float2(y1i1, y1s1);
      *(float2*)(etv + (size_t)nsp * N_NEUR + nb) =
          make_float2(ev0 ? 1.0f : 0.0f, ev1 ? 1.0f : 0.0f);
    }
    nsp += has ? 1 : 0;

    ii0 = has ? (y1i0 + wv0) : y1i0;
    ii1 = has ? (y1i1 + wv1) : y1i1;
    vv0 = y1v0 - (ev0 ? 1.0f : 0.0f);
    vv1 = y1v1 - (ev1 ? 1.0f : 0.0f);
    if (USE_SRES) {
      ss0 = ev0 ? sr0 : y1s0;
      ss1 = ev1 ? sr1 : y1s1;
    } else {
      ss0 = y1s0; ss1 = y1s1;
      if (ev0 | ev1) {
        uint32_t f0 = 0u, f1 = (uint32_t)k;
        tf2x32(kt0, kt1, f0, f1);
        if (ev0) {
          uint32_t c0 = (uint32_t)(nb < HALF_N ? nb : nb - HALF_N);
          uint32_t c1 = c0 + HALF_N;
          tf2x32(f0, f1, c0, c1);
          ss0 = xla_log(u01_from_bits(nb < HALF_N ? c0 : c1)) - 0.01f;
        }
        if (ev1) {
          int j = nb + 1;
          uint32_t c0 = (uint32_t)(j < HALF_N ? j : j - HALF_N);
          uint32_t c1 = c0 + HALF_N;
          tf2x32(f0, f1, c0, c1);
          ss1 = xla_log(u01_from_bits(j < HALF_N ? c0 : c1)) - 0.01f;
        }
      }
    }

    ((float2*)yrow)[0] = make_float2(vv0, ii0);
    ((float2*)yrow)[1] = make_float2(ss0, vv1);
    ((float2*)yrow)[2] = make_float2(ii1, ss1);
    yrow += (size_t)N_NEUR * 3;
  }

  if (tid == 0) nspp[0] = (float)nsp;
}

extern "C" void kernel_launch(void* const* d_in, const int* in_sizes, int n_in,
                              void* d_out, int out_size, void* d_ws, size_t ws_size,
                              hipStream_t stream) {
  const float* ts = (const float*)d_in[0];
  const float* v0 = (const float*)d_in[1];
  const float* i0 = (const float*)d_in[2];
  const float* ic = (const float*)d_in[3];
  const float* w  = (const float*)d_in[4];
  const float* mu = (const float*)d_in[5];
  const int* seed = (const int*)d_in[6];

  const int T = in_sizes[0];      // 4000
  const int N = in_sizes[1];      // 2048
  long long rem = (long long)out_size - (long long)T * N * 3 - 1;
  int MS = (int)(rem / (1 + 4 * (long long)N));
  if (MS <= 0) MS = 512;

  size_t inf_base = (size_t)T * N * 3;
  size_t inf_cnt  = (size_t)MS + (size_t)MS * N * 3;
  size_t zero_cnt = (size_t)MS * N;
  snn_init<<<dim3(512), dim3(256), 0, stream>>>((float*)d_out, inf_base, inf_cnt, zero_cnt);

  // ws layout: [0, sres_bytes) = sres; [sres_bytes, +4*(T-1)) = spk
  size_t sres_bytes = (size_t)(T - 1) * (size_t)N * sizeof(float);
  size_t full_bytes = sres_bytes + (size_t)(T - 1) * sizeof(uint32_t);

  if (ws_size >= full_bytes) {
    float* sres = (float*)d_ws;
    uint32_t* spk = (uint32_t*)((char*)d_ws + sres_bytes);
    snn_pre<<<dim3(T - 1), dim3(1024), 0, stream>>>(seed, sres);
    snn_evt<<<dim3(1), dim3(1024), 0, stream>>>(ts, v0, i0, ic, w, mu, seed,
                                                sres, spk, (float*)d_out, T, MS);
    int nseg = (T - 1 + CKPT - 1) / CKPT;
    snn_rep<<<dim3(nseg * 2), dim3(1024), 0, stream>>>(ts, ic, w, mu, sres, spk,
                                                       (float*)d_out, T, MS);
  } else if (ws_size >= sres_bytes) {
    snn_pre<<<dim3(T - 1), dim3(1024), 0, stream>>>(seed, (float*)d_ws);
    snn_sim<true><<<dim3(1), dim3(1024), 0, stream>>>(ts, v0, i0, ic, w, mu, seed,
                                                      (const float*)d_ws,
                                                      (float*)d_out, T, MS);
  } else {
    snn_sim<false><<<dim3(1), dim3(1024), 0, stream>>>(ts, v0, i0, ic, w, mu, seed,
                                                       nullptr, (float*)d_out, T, MS);
  }
}

// Round 11
// 2916.431 us; speedup vs baseline: 1.1664x; 1.0212x over previous
//
#include <hip/hip_runtime.h>
#include <stdint.h>

// ====== variant switches for XLA:CPU transcendental reconstruction ======
// (verified bit-exact in round 1 — DO NOT change the math)
#define XLA_LOG_TAIL_A 1
#define XLA_USE_FMA    0

#if XLA_USE_FMA
#define MADD(a,b,c) __builtin_fmaf((a),(b),(c))
#else
#define MADD(a,b,c) ((a)*(b)+(c))
#endif

#define N_NEUR 2048
#define HALF_N 1024
#define CKPT   124      // even: checkpoints land on even (pair-start) steps

// ---------------- threefry2x32 (exact JAX primitive) ----------------
__device__ __forceinline__ uint32_t rotl32(uint32_t x, int r) {
  return (x << r) | (x >> (32 - r));
}

__device__ __forceinline__ void tf2x32(uint32_t k0, uint32_t k1,
                                       uint32_t& x0, uint32_t& x1) {
  const uint32_t k2 = k0 ^ k1 ^ 0x1BD11BDAu;
  x0 += k0; x1 += k1;
#define TF_R(r) { x0 += x1; x1 = rotl32(x1, r); x1 ^= x0; }
  TF_R(13) TF_R(15) TF_R(26) TF_R(6)
  x0 += k1; x1 += k2 + 1u;
  TF_R(17) TF_R(29) TF_R(16) TF_R(24)
  x0 += k2; x1 += k0 + 2u;
  TF_R(13) TF_R(15) TF_R(26) TF_R(6)
  x0 += k0; x1 += k1 + 3u;
  TF_R(17) TF_R(29) TF_R(16) TF_R(24)
  x0 += k1; x1 += k2 + 4u;
  TF_R(13) TF_R(15) TF_R(26) TF_R(6)
  x0 += k2; x1 += k0 + 5u;
#undef TF_R
}

__device__ __forceinline__ float u01_from_bits(uint32_t bits) {
#pragma clang fp contract(off)
  float f = __uint_as_float((bits >> 9) | 0x3f800000u);
  return f - 1.0f;
}

// ---------------- XLA:CPU GenerateVF32Log (Cephes, Estrin poly) ----------------
__device__ __forceinline__ float xla_log(float xin) {
#pragma clang fp contract(off)
  float t0 = fmaxf(xin, __uint_as_float(0x00800000u));
  uint32_t bits = __float_as_uint(t0);
  int em = (int)(bits >> 23) - 127;
  t0 = __uint_as_float((bits & 0x807fffffu) | 0x3f000000u);
  float e = 1.0f + (float)em;
  const bool mlt = t0 < (float)0.707106781186547524;
  float tmp1 = mlt ? t0 : 0.0f;
  t0 = t0 - 1.0f;
  e = e - (mlt ? 1.0f : 0.0f);
  t0 = t0 + tmp1;
  float x2 = t0 * t0;
  float x3 = x2 * t0;
  float y  = MADD(t0, (float)7.0376836292E-2, (float)-1.1514610310E-1);
  float ya = MADD(t0, (float)-1.2420140846E-1, (float)1.4249322787E-1);
  float yb = MADD(t0, (float)2.0000714765E-1, (float)-2.4999993993E-1);
  y  = MADD(y,  t0, (float)1.1676998740E-1);
  ya = MADD(ya, t0, (float)-1.6668057665E-1);
  yb = MADD(yb, t0, (float)3.3333331174E-1);
  y  = MADD(y, x3, ya);
  y  = MADD(y, x3, yb);
  y  = y * x3;
  float ey1 = e * (float)-2.12194440e-4;
  float hx2 = x2 * 0.5f;
  y = y + ey1;
  t0 = t0 - hx2;
  float ey2 = e * (float)0.693359375;
#if XLA_LOG_TAIL_A
  t0 = t0 + y;
  t0 = t0 + ey2;
#else
  t0 = t0 + ey2;
  t0 = t0 + y;
#endif
  if (xin == 0.0f) return -__builtin_inff();
  return t0;
}

// ---------------- XLA:CPU GenerateVF32Exp (old Cephes structure) ----------------
__device__ __forceinline__ float xla_exp(float xin) {
#pragma clang fp contract(off)
  float x = fmaxf(xin, (float)-88.3762626647949);
  x = fminf(x, (float)88.3762626647950);
  float fx = floorf(MADD(x, (float)1.44269504088896341, 0.5f));
  float tmp = (float)0.693359375 * fx;
  float z = (float)-2.12194440e-4 * fx;
  x = x - tmp;
  x = x - z;
  z = x * x;
  float y = MADD(x, (float)1.9875691500E-4, (float)1.3981999507E-3);
  y = MADD(y, x, (float)8.3334519073E-3);
  y = MADD(y, x, (float)4.1665795894E-2);
  y = MADD(y, x, (float)1.6666665459E-1);
  y = MADD(y, x, (float)5.0000001201E-1);
  y = MADD(y, z, x);
  y = 1.0f + y;
  int n = (int)fx;
  float p2n = __uint_as_float((uint32_t)(n + 127) << 23);
  return fmaxf(y * p2n, xin);
}

__device__ __forceinline__ float xla_log1p(float x) {
#pragma clang fp contract(off)
  float fl = xla_log(x + 1.0f);
  float fs = ((-0.5f * x) + 1.0f) * x;
  return (fabsf(x) < (float)1e-4) ? fs : fl;
}

// jax.nn.softplus(v) = max(v,0) + log1p(exp(-|v|))
__device__ __forceinline__ float softplus_xla(float v) {
#pragma clang fp contract(off)
  // exact shortcut: for v>=16, exp(-v)<=1.13e-7 < ulp(v)/2 -> sum rounds to v
  if (v >= 16.0f) return v;
  float a = fabsf(v);
  float ex = xla_exp(-a);
  float lp = xla_log1p(ex);
  return fmaxf(v, 0.0f) + lp;
}

// ---------------- init: tevents/yevents = +inf, event_types = 0 ----------------
__global__ void snn_init(float* __restrict__ out, size_t inf_base,
                         size_t inf_cnt, size_t zero_cnt) {
  size_t i = (size_t)blockIdx.x * blockDim.x + threadIdx.x;
  size_t stride = (size_t)gridDim.x * blockDim.x;
  size_t total = inf_cnt + zero_cnt;
  for (size_t k = i; k < total; k += stride) {
    out[inf_base + k] = (k < inf_cnt) ? __builtin_inff() : 0.0f;
  }
}

// ------- precompute s_reset into FUSED pair layout --------------------------
// sres2[(k>>1)*2N + (j>>1)*4 + (k&1)*2 + (j&1)] = log(u_k[j]) - alpha
// -> pair P, thread tid owns float4 {E_nb, E_nb+1, O_nb, O_nb+1} at
//    sres2 + P*2N + tid*4   (nb = 2*tid)
__global__ __launch_bounds__(1024)
void snn_pre(const int* __restrict__ seedp, float* __restrict__ sres2) {
#pragma clang fp contract(off)
  const int step = blockIdx.x;       // 0..T-2
  const int t = threadIdx.x;
  uint32_t seed = (uint32_t)seedp[0];
  uint32_t a0 = 0u, a1 = 2u; tf2x32(0u, seed, a0, a1);
  uint32_t b0 = 1u, b1 = 3u; tf2x32(0u, seed, b0, b1);
  uint32_t f0 = 0u, f1 = (uint32_t)step; tf2x32(a1, b1, f0, f1);
  uint32_t d0 = (uint32_t)t, d1 = (uint32_t)(t + HALF_N);
  tf2x32(f0, f1, d0, d1);
  float srA = xla_log(u01_from_bits(d0)) - 0.01f;   // j = t
  float srB = xla_log(u01_from_bits(d1)) - 0.01f;   // j = t + 1024
  size_t base = (size_t)(step >> 1) * (2 * N_NEUR) + (size_t)(step & 1) * 2;
  sres2[base + (size_t)(t >> 1) * 4 + (t & 1)] = srA;
  sres2[base + (size_t)((t >> 1) + 512) * 4 + (t & 1)] = srB;
}

// ============ PHASE A: decision chain, 2 steps/barrier, 16 waves ==============
// 1024 thr x 2 contiguous neurons. Fused sres float4/pair; unroll-2 pair loop.
__global__ __launch_bounds__(1024, 1)
void snn_evt(const float* __restrict__ ts, const float* __restrict__ v0,
             const float* __restrict__ i0, const float* __restrict__ ic,
             const float* __restrict__ w, const float* __restrict__ mu,
             const int* __restrict__ seedp, const float* __restrict__ sres2,
             uint32_t* __restrict__ spk, float* __restrict__ out, int T, int MS) {
#pragma clang fp contract(off)
  const int tid = threadIdx.x;
  const int nb = tid * 2;               // neurons nb, nb+1
  const int lane = tid & 63;

  float* ys   = out;                                     // [T][N][3]
  float* tev  = out + (size_t)T * N_NEUR * 3;            // [MS]
  float* etv  = tev + (size_t)MS + (size_t)MS * N_NEUR * 3;
  float* nspp = etv + (size_t)MS * N_NEUR;               // [1]

  // keys
  uint32_t seed = (uint32_t)seedp[0];
  uint32_t a0 = 0u, a1 = 2u; tf2x32(0u, seed, a0, a1);
  uint32_t b0 = 1u, b1 = 3u; tf2x32(0u, seed, b0, b1);
  const uint32_t ki0 = a0, ki1 = b0;

  const float m0 = mu[0], m1 = mu[1];

  // carried state (E = even step committed, O = odd step)
  float vvO[2], ssE[2], y1iP[2], wEp[2], wOp[2], icv[2], srE[2], srO[2];
  bool  evO[2];
  bool  hasEp = false, hasOp = false;
  float dtOp = 0.0f;   // 0 => prologue zero-dt trick

  { float2 x = *(const float2*)&v0[nb]; vvO[0]=x.x; vvO[1]=x.y; }
  { float2 x = *(const float2*)&i0[nb]; y1iP[0]=x.x; y1iP[1]=x.y; }
  { float2 x = *(const float2*)&ic[nb]; icv[0]=x.x; icv[1]=x.y; }
#pragma unroll
  for (int q = 0; q < 2; ++q) {
    int j = nb + q;
    uint32_t c0 = (uint32_t)(j < HALF_N ? j : j - HALF_N);
    uint32_t c1 = c0 + HALF_N;
    tf2x32(ki0, ki1, c0, c1);
    ssE[q] = xla_log(u01_from_bits(j < HALF_N ? c0 : c1)) - 0.01f;
    evO[q] = false;
    wEp[q] = 0.0f; wOp[q] = 0.0f;
  }
  {
    float4 x = *(const float4*)(sres2 + (size_t)tid * 4);   // pair 0
    srE[0]=x.x; srE[1]=x.y; srO[0]=x.z; srO[1]=x.w;
  }

  __shared__ alignas(8) uint32_t slot[4][2];   // [pair&3][E/O]
  if (tid < 8) ((uint32_t*)slot)[tid] = 0xFFFFFFFFu;
  __syncthreads();

  int nsp = 0;
  int next_ck = 0;
  float tsE = ts[0];
  const int pairs = (T - 1) >> 1;
  const int npairs_tab = T >> 1;        // sres2 pair rows available

  #pragma unroll 2
  for (int P = 0; P < pairs; ++P) {
    const int e = 2 * P;

    // ---- early issues: ts, next-pair sres (one dwordx4), slot reset ----
    const float tsE1 = ts[e + 1];
    const float tsE2 = ts[e + 2];
    float srEn[2], srOn[2];
    {
      int pn = P + 1;  if (pn >= npairs_tab) pn = npairs_tab - 1;
      float4 x = *(const float4*)(sres2 + (size_t)pn * (2 * N_NEUR) + (size_t)tid * 4);
      srEn[0]=x.x; srEn[1]=x.y; srOn[0]=x.z; srOn[1]=x.w;
    }
    if (tid == 1) {
      slot[(P + 2) & 3][0] = 0xFFFFFFFFu;
      slot[(P + 2) & 3][1] = 0xFFFFFFFFu;
    }

    // ---- A: finish deferred step o_prev (consumes w loaded last pair) ----
    float vvE[2], iiE[2], y1iO_[2];
#pragma unroll
    for (int q = 0; q < 2; ++q) {
      float iiO = hasEp ? (y1iP[q] + wEp[q]) : y1iP[q];
      float dv  = m0 * ((iiO + icv[q]) - vvO[q]);
      float y1v = vvO[q] + dtOp * dv;
      float y1i = iiO + dtOp * ((-m1) * iiO);
      vvE[q] = y1v - (evO[q] ? 1.0f : 0.0f);
      y1iO_[q] = y1i;
    }
#pragma unroll
    for (int q = 0; q < 2; ++q)
      iiE[q] = hasOp ? (y1iO_[q] + wOp[q]) : y1iO_[q];

    // ---- checkpoint (rare, uniform) ----
    if (e == next_ck) {
      float* yr = ys + ((size_t)e * N_NEUR + nb) * 3;
      ((float2*)yr)[0] = make_float2(vvE[0], iiE[0]);
      ((float2*)yr)[1] = make_float2(ssE[0], vvE[1]);
      ((float2*)yr)[2] = make_float2(iiE[1], ssE[1]);
      next_ck += CKPT;
    }

    const float dtE = tsE1 - tsE;
    const float dtO = tsE2 - tsE1;

    // ---- two event steps, lane-local (expressions verbatim) ----
    float y1iE[2], vvOn[2], ssEn[2];
    bool evE[2], evOn[2];
#pragma unroll
    for (int q = 0; q < 2; ++q) {
      float sp  = softplus_xla(vvE[q]);
      float y1s = ssE[q] + dtE * sp;
      evE[q] = (y1s >= 0.0f);
      float dv  = m0 * ((iiE[q] + icv[q]) - vvE[q]);
      float y1v = vvE[q] + dtE * dv;
      y1iE[q] = iiE[q] + dtE * ((-m1) * iiE[q]);
      vvOn[q] = y1v - (evE[q] ? 1.0f : 0.0f);
      float ssO_ = evE[q] ? srE[q] : y1s;
      float spO = softplus_xla(vvOn[q]);
      float y1sO = ssO_ + dtO * spO;
      evOn[q] = (y1sO >= 0.0f);
      ssEn[q] = evOn[q] ? srO[q] : y1sO;
    }

    // ---- candidates: ballot -> lane0 atomicMin ----
    {
      int lE = evE[0] ? 0 : (evE[1] ? 1 : 2);
      int lO = evOn[0] ? 0 : (evOn[1] ? 1 : 2);
      unsigned long long bE = __ballot(lE < 2);
      unsigned long long bO = __ballot(lO < 2);
      if (lane == 0) {
        if (bE) {
          uint32_t cE = (uint32_t)__builtin_amdgcn_readlane(nb + lE, __builtin_ctzll(bE));
          atomicMin(&slot[P & 3][0], cE);
        }
        if (bO) {
          uint32_t cO = (uint32_t)__builtin_amdgcn_readlane(nb + lO, __builtin_ctzll(bO));
          atomicMin(&slot[P & 3][1], cO);
        }
      }
    }

    __syncthreads();

    // ---- combined minima (8B broadcast read) ----
    uint2 rr = *(const uint2*)&slot[P & 3][0];
    uint32_t gE = (uint32_t)__builtin_amdgcn_readfirstlane((int)rr.x);
    uint32_t gO = (uint32_t)__builtin_amdgcn_readfirstlane((int)rr.y);
    const bool hasE = (gE != 0xFFFFFFFFu);
    const bool hasO = (gO != 0xFFFFFFFFu);

    // ---- bookkeeping (tid0) ----
    if (tid == 0) {
      spk[e] = ((uint32_t)nsp << 16) | (hasE ? (gE & 0xFFFFu) : 0xFFFFu);
      if (hasE && nsp < MS) tev[nsp] = tsE1;
    }
    int nspE = nsp + (hasE ? 1 : 0);
    if (tid == 0) {
      spk[e + 1] = ((uint32_t)nspE << 16) | (hasO ? (gO & 0xFFFFu) : 0xFFFFu);
      if (hasO && nspE < MS) tev[nspE] = tsE2;
    }
    nsp = nspE + (hasO ? 1 : 0);

    // ---- issue w loads (consumed next pair) ----
    float wEn[2] = {0, 0}, wOn[2] = {0, 0};
    if (hasE) {
      float2 x = *(const float2*)&w[((size_t)gE << 11) + nb];
      wEn[0]=x.x; wEn[1]=x.y;
    }
    if (hasO) {
      float2 x = *(const float2*)&w[((size_t)gO << 11) + nb];
      wOn[0]=x.x; wOn[1]=x.y;
    }

    // ---- rotate carries (renamed away under unroll) ----
#pragma unroll
    for (int q = 0; q < 2; ++q) {
      vvO[q] = vvOn[q];
      ssE[q] = ssEn[q];
      evO[q] = evOn[q];
      y1iP[q] = y1iE[q];
      wEp[q] = wEn[q];
      wOp[q] = wOn[q];
      srE[q] = srEn[q];
      srO[q] = srOn[q];
    }
    hasEp = hasE; hasOp = hasO;
    dtOp = dtO;
    tsE = tsE2;
  }

  // ---- epilogue: leftover last step (T-1 odd) ----
  if ((T - 1) & 1) {
    const int e = T - 2;
    float vvE[2], iiE[2];
#pragma unroll
    for (int q = 0; q < 2; ++q) {
      float iiO = hasEp ? (y1iP[q] + wEp[q]) : y1iP[q];
      float dv  = m0 * ((iiO + icv[q]) - vvO[q]);
      float y1v = vvO[q] + dtOp * dv;
      float y1i = iiO + dtOp * ((-m1) * iiO);
      vvE[q] = y1v - (evO[q] ? 1.0f : 0.0f);
      iiE[q] = hasOp ? (y1i + wOp[q]) : y1i;
    }
    if (e == next_ck) {
      float* yr = ys + ((size_t)e * N_NEUR + nb) * 3;
      ((float2*)yr)[0] = make_float2(vvE[0], iiE[0]);
      ((float2*)yr)[1] = make_float2(ssE[0], vvE[1]);
      ((float2*)yr)[2] = make_float2(iiE[1], ssE[1]);
    }
    const float tsE1 = ts[T - 1];
    const float dtE = tsE1 - tsE;
    bool evE[2];
#pragma unroll
    for (int q = 0; q < 2; ++q) {
      float sp  = softplus_xla(vvE[q]);
      float y1s = ssE[q] + dtE * sp;
      evE[q] = (y1s >= 0.0f);
    }
    int lE = evE[0] ? 0 : (evE[1] ? 1 : 2);
    unsigned long long bE = __ballot(lE < 2);
    if (lane == 0 && bE) {
      uint32_t cE = (uint32_t)__builtin_amdgcn_readlane(nb + lE, __builtin_ctzll(bE));
      atomicMin(&slot[pairs & 3][0], cE);
    }
    __syncthreads();
    uint32_t gE = (uint32_t)__builtin_amdgcn_readfirstlane((int)slot[pairs & 3][0]);
    const bool hasE = (gE != 0xFFFFFFFFu);
    if (tid == 0) {
      spk[e] = ((uint32_t)nsp << 16) | (hasE ? (gE & 0xFFFFu) : 0xFFFFu);
      if (hasE && nsp < MS) tev[nsp] = tsE1;
    }
    nsp += hasE ? 1 : 0;
  }

  if (tid == 0) nspp[0] = (float)nsp;
}

// ============ PHASE B: parallel replay (segments x 2 halves, 1 n/t) ===========
__global__ __launch_bounds__(1024, 1)
void snn_rep(const float* __restrict__ ts, const float* __restrict__ ic,
             const float* __restrict__ w, const float* __restrict__ mu,
             const float* __restrict__ sres2, const uint32_t* __restrict__ spk,
             float* __restrict__ out, int T, int MS) {
#pragma clang fp contract(off)
  const int seg = blockIdx.x >> 1;
  const int gn = (blockIdx.x & 1) * 1024 + threadIdx.x;
  const int lo = seg * CKPT;
  const int end = min(lo + CKPT, T - 1);

  float* ys  = out;                                      // [T][N][3]
  float* tev = out + (size_t)T * N_NEUR * 3;
  float* yev = tev + (size_t)MS;                         // [MS][N][3]
  float* etv = yev + (size_t)MS * N_NEUR * 3;            // [MS][N]

  const float* y0r = ys + ((size_t)lo * N_NEUR + gn) * 3;
  float vv = y0r[0];
  float ii = y0r[1];
  float ss = y0r[2];
  const float icv = ic[gn];
  const float m0 = mu[0], m1 = mu[1];
  float tp = ts[lo];
  const size_t sbase = (size_t)(gn >> 1) * 4 + (size_t)(gn & 1);

  for (int k = lo; k < end; ++k) {
    const float tn = ts[k + 1];
    const float dt = tn - tp;
    tp = tn;
    const uint32_t pk = spk[k];

    float sp  = softplus_xla(vv);
    float y1s = ss + dt * sp;
    const bool ev = (y1s >= 0.0f);
    float dv  = m0 * ((ii + icv) - vv);
    float y1v = vv + dt * dv;
    float y1i = ii + dt * ((-m1) * ii);

    const uint32_t e16 = pk & 0xFFFFu;
    const bool has = (e16 != 0xFFFFu);
    const uint32_t nsp = pk >> 16;

    float wv = 0.0f;
    if (has) wv = w[((size_t)e16 << 11) + gn];

    if (has && nsp < (uint32_t)MS) {
      float* ye = yev + ((size_t)nsp * N_NEUR + gn) * 3;
      ye[0] = y1v; ye[1] = y1i; ye[2] = y1s;
      etv[(size_t)nsp * N_NEUR + gn] = ev ? 1.0f : 0.0f;
    }

    ii = has ? (y1i + wv) : y1i;
    vv = y1v - (ev ? 1.0f : 0.0f);
    if (ev)
      ss = sres2[(size_t)(k >> 1) * (2 * N_NEUR) + sbase + (size_t)(k & 1) * 2];
    else
      ss = y1s;

    float* yr = ys + ((size_t)(k + 1) * N_NEUR + gn) * 3;
    yr[0] = vv; yr[1] = ii; yr[2] = ss;
  }
}

// ============ FALLBACK: single-kernel scan (if workspace too small) ===========
template <bool USE_SRES>
__global__ __launch_bounds__(1024, 1)
void snn_sim(const float* __restrict__ ts, const float* __restrict__ v0,
             const float* __restrict__ i0, const float* __restrict__ ic,
             const float* __restrict__ w, const float* __restrict__ mu,
             const int* __restrict__ seedp, const float* __restrict__ sres2,
             float* __restrict__ out, int T, int MS) {
#pragma clang fp contract(off)
  const int tid = threadIdx.x;
  const int nb = tid * 2;
  const int lane = tid & 63;

  float* ys   = out;
  float* tev  = out + (size_t)T * N_NEUR * 3;
  float* yev  = tev + (size_t)MS;
  float* etv  = yev + (size_t)MS * N_NEUR * 3;
  float* nspp = etv + (size_t)MS * N_NEUR;

  uint32_t seed = (uint32_t)seedp[0];
  uint32_t a0 = 0u, a1 = 2u; tf2x32(0u, seed, a0, a1);
  uint32_t b0 = 1u, b1 = 3u; tf2x32(0u, seed, b0, b1);
  const uint32_t ki0 = a0, ki1 = b0;
  const uint32_t kt0 = a1, kt1 = b1;

  float vv0, vv1, ii0, ii1, ss0, ss1, icv0, icv1;
  { float2 x = *(const float2*)&v0[nb]; vv0 = x.x; vv1 = x.y; }
  { float2 x = *(const float2*)&i0[nb]; ii0 = x.x; ii1 = x.y; }
  { float2 x = *(const float2*)&ic[nb]; icv0 = x.x; icv1 = x.y; }
  {
    uint32_t c0 = (uint32_t)(nb < HALF_N ? nb : nb - HALF_N);
    uint32_t c1 = c0 + HALF_N;
    tf2x32(ki0, ki1, c0, c1);
    ss0 = xla_log(u01_from_bits(nb < HALF_N ? c0 : c1)) - 0.01f;
  }
  {
    int j = nb + 1;
    uint32_t c0 = (uint32_t)(j < HALF_N ? j : j - HALF_N);
    uint32_t c1 = c0 + HALF_N;
    tf2x32(ki0, ki1, c0, c1);
    ss1 = xla_log(u01_from_bits(j < HALF_N ? c0 : c1)) - 0.01f;
  }
  const float m0 = mu[0], m1 = mu[1];

  {
    float* yr = ys + (size_t)nb * 3;
    ((float2*)yr)[0] = make_float2(vv0, ii0);
    ((float2*)yr)[1] = make_float2(ss0, vv1);
    ((float2*)yr)[2] = make_float2(ii1, ss1);
  }

  __shared__ uint32_t slot[4];
  if (tid < 4) slot[tid] = 0xFFFFFFFFu;
  __syncthreads();

  int nsp = 0;
  float tp = ts[0];
  float* yrow = ys + (size_t)N_NEUR * 3 + (size_t)nb * 3;

  for (int k = 0; k < T - 1; ++k) {
    const float tn = ts[k + 1];
    const float dt = tn - tp;
    tp = tn;

    float sr0 = 0.0f, sr1 = 0.0f;
    if (USE_SRES) {
      float2 x = *(const float2*)(sres2 + (size_t)(k >> 1) * (2 * N_NEUR) +
                                  (size_t)tid * 4 + (size_t)(k & 1) * 2);
      sr0 = x.x; sr1 = x.y;
    }

    float sp0 = softplus_xla(vv0);
    float sp1 = softplus_xla(vv1);
    float y1s0 = ss0 + dt * sp0;
    float y1s1 = ss1 + dt * sp1;
    const bool ev0 = (y1s0 >= 0.0f);
    const bool ev1 = (y1s1 >= 0.0f);

    int lidx = ev0 ? 0 : (ev1 ? 1 : 2);
    unsigned long long bm = __ballot(lidx < 2);
    if (lane == 0 && bm) {
      int fl = __builtin_ctzll(bm);
      uint32_t cand = (uint32_t)__builtin_amdgcn_readlane(nb + lidx, fl);
      atomicMin(&slot[k & 3], cand);
    }
    if (tid == 0) slot[(k + 1) & 3] = 0xFFFFFFFFu;

    float dv0 = m0 * ((ii0 + icv0) - vv0);
    float dv1 = m0 * ((ii1 + icv1) - vv1);
    float y1v0 = vv0 + dt * dv0;
    float y1v1 = vv1 + dt * dv1;
    float y1i0 = ii0 + dt * ((-m1) * ii0);
    float y1i1 = ii1 + dt * ((-m1) * ii1);

    __syncthreads();

    uint32_t gmin = (uint32_t)__builtin_amdgcn_readfirstlane((int)slot[k & 3]);
    const bool has = (gmin != 0xFFFFFFFFu);

    float wv0 = 0.0f, wv1 = 0.0f;
    if (has) {
      float2 x = *(const float2*)&w[((size_t)gmin << 11) + nb];
      wv0 = x.x; wv1 = x.y;
    }

    if (has && nsp < MS) {
      if (tid == 0) tev[nsp] = tn;
      float* ye = yev + ((size_t)nsp * N_NEUR + nb) * 3;
      ((float2*)ye)[0] = make_float2(y1v0, y1i0);
      ((float2*)ye)[1] = make_float2(y1s0, y1v1);
      ((float2*)ye)[2] = make_float2(y1i1, y1s1);
      *(float2*)(etv + (size_t)nsp * N_NEUR + nb) =
          make_float2(ev0 ? 1.0f : 0.0f, ev1 ? 1.0f : 0.0f);
    }
    nsp += has ? 1 : 0;

    ii0 = has ? (y1i0 + wv0) : y1i0;
    ii1 = has ? (y1i1 + wv1) : y1i1;
    vv0 = y1v0 - (ev0 ? 1.0f : 0.0f);
    vv1 = y1v1 - (ev1 ? 1.0f : 0.0f);
    if (USE_SRES) {
      ss0 = ev0 ? sr0 : y1s0;
      ss1 = ev1 ? sr1 : y1s1;
    } else {
      ss0 = y1s0; ss1 = y1s1;
      if (ev0 | ev1) {
        uint32_t f0 = 0u, f1 = (uint32_t)k;
        tf2x32(kt0, kt1, f0, f1);
        if (ev0) {
          uint32_t c0 = (uint32_t)(nb < HALF_N ? nb : nb - HALF_N);
          uint32_t c1 = c0 + HALF_N;
          tf2x32(f0, f1, c0, c1);
          ss0 = xla_log(u01_from_bits(nb < HALF_N ? c0 : c1)) - 0.01f;
        }
        if (ev1) {
          int j = nb + 1;
          uint32_t c0 = (uint32_t)(j < HALF_N ? j : j - HALF_N);
          uint32_t c1 = c0 + HALF_N;
          tf2x32(f0, f1, c0, c1);
          ss1 = xla_log(u01_from_bits(j < HALF_N ? c0 : c1)) - 0.01f;
        }
      }
    }

    ((float2*)yrow)[0] = make_float2(vv0, ii0);
    ((float2*)yrow)[1] = make_float2(ss0, vv1);
    ((float2*)yrow)[2] = make_float2(ii1, ss1);
    yrow += (size_t)N_NEUR * 3;
  }

  if (tid == 0) nspp[0] = (float)nsp;
}

extern "C" void kernel_launch(void* const* d_in, const int* in_sizes, int n_in,
                              void* d_out, int out_size, void* d_ws, size_t ws_size,
                              hipStream_t stream) {
  const float* ts = (const float*)d_in[0];
  const float* v0 = (const float*)d_in[1];
  const float* i0 = (const float*)d_in[2];
  const float* ic = (const float*)d_in[3];
  const float* w  = (const float*)d_in[4];
  const float* mu = (const float*)d_in[5];
  const int* seed = (const int*)d_in[6];

  const int T = in_sizes[0];      // 4000
  const int N = in_sizes[1];      // 2048
  long long rem = (long long)out_size - (long long)T * N * 3 - 1;
  int MS = (int)(rem / (1 + 4 * (long long)N));
  if (MS <= 0) MS = 512;

  size_t inf_base = (size_t)T * N * 3;
  size_t inf_cnt  = (size_t)MS + (size_t)MS * N * 3;
  size_t zero_cnt = (size_t)MS * N;
  snn_init<<<dim3(512), dim3(256), 0, stream>>>((float*)d_out, inf_base, inf_cnt, zero_cnt);

  // ws layout: [0, sres2_bytes) = fused sres; then spk
  int npairs_tab = T >> 1;   // ceil((T-1)/2)
  size_t sres2_bytes = (size_t)npairs_tab * 2 * (size_t)N * sizeof(float);
  size_t full_bytes = sres2_bytes + (size_t)(T - 1) * sizeof(uint32_t);

  if (ws_size >= full_bytes) {
    float* sres2 = (float*)d_ws;
    uint32_t* spk = (uint32_t*)((char*)d_ws + sres2_bytes);
    snn_pre<<<dim3(T - 1), dim3(1024), 0, stream>>>(seed, sres2);
    snn_evt<<<dim3(1), dim3(1024), 0, stream>>>(ts, v0, i0, ic, w, mu, seed,
                                                sres2, spk, (float*)d_out, T, MS);
    int nseg = (T - 1 + CKPT - 1) / CKPT;
    snn_rep<<<dim3(nseg * 2), dim3(1024), 0, stream>>>(ts, ic, w, mu, sres2, spk,
                                                       (float*)d_out, T, MS);
  } else if (ws_size >= sres2_bytes) {
    snn_pre<<<dim3(T - 1), dim3(1024), 0, stream>>>(seed, (float*)d_ws);
    snn_sim<true><<<dim3(1), dim3(1024), 0, stream>>>(ts, v0, i0, ic, w, mu, seed,
                                                      (const float*)d_ws,
                                                      (float*)d_out, T, MS);
  } else {
    snn_sim<false><<<dim3(1), dim3(1024), 0, stream>>>(ts, v0, i0, ic, w, mu, seed,
                                                       nullptr, (float*)d_out, T, MS);
  }
}